// Round 2
// baseline (2700.107 us; speedup 1.0000x reference)
//
#include <hip/hip_runtime.h>
#include <cmath>

#define EPSV 1e-20f

typedef _Float16 f16;

__device__ __forceinline__ float softplusf(float x) {
    return fmaxf(x, 0.f) + log1pf(expf(-fabsf(x)));
}

// ---------------------------------------------------------------------------
// Weight prep: wp = softplus(w_raw), s[co] = sum over (ci,kh,kw).
// Offsets into WB (floats):
// wp1@0(200) s1@200(8) wp2@208(1600) s2@1808(8) wp3@1816(1600) s3@3416(8)
// wp4@3424(1152) s4@4576(8) wp5@4584(1152) s5@5736(8) wp6@5744(1152) s6@6896(8)
// wp7@6904(8) s7@6912(1)   total 6913 floats
// ---------------------------------------------------------------------------
__global__ void prep_weights(const float* __restrict__ w1, const float* __restrict__ w2,
                             const float* __restrict__ w3, const float* __restrict__ w4,
                             const float* __restrict__ w5, const float* __restrict__ w6,
                             const float* __restrict__ w7, float* __restrict__ wsw) {
    __shared__ float lds[1600];
    const float* srcs[7] = {w1, w2, w3, w4, w5, w6, w7};
    const int ns[7]    = {200, 1600, 1600, 1152, 1152, 1152, 8};
    const int pers[7]  = {25, 200, 200, 144, 144, 144, 8};
    const int couts[7] = {8, 8, 8, 8, 8, 8, 1};
    const int offs[7]  = {0, 208, 1816, 3424, 4584, 5744, 6904};
    const int soffs[7] = {200, 1808, 3416, 4576, 5736, 6896, 6912};

    int t = blockIdx.x;
    const float* src = srcs[t];
    int n = ns[t];
    for (int i = threadIdx.x; i < n; i += blockDim.x) {
        float v = softplusf(src[i]);
        lds[i] = v;
        wsw[offs[t] + i] = v;
    }
    __syncthreads();
    int per = pers[t];
    if ((int)threadIdx.x < couts[t]) {
        float s = 0.f;
        for (int i = 0; i < per; ++i) s += lds[threadIdx.x * per + i];
        wsw[soffs[t] + threadIdx.x] = s;
    }
}

// ---------------------------------------------------------------------------
// Encoder nconv: CIN -> 8 channels, KxK, zero pad (K-1)/2.
// One thread computes all 8 output channels at one pixel. fp32 accumulate.
// ---------------------------------------------------------------------------
template <typename Tin, typename Tout, int CIN, int K>
__global__ void __launch_bounds__(256) nconv_enc(
    const Tin* __restrict__ xin, const Tin* __restrict__ cin,
    const float* __restrict__ wp, const float* __restrict__ ssum,
    const float* __restrict__ bias,
    Tout* __restrict__ xout, Tout* __restrict__ cout,
    int B, int H, int W) {
    constexpr int COUT = 8;
    constexpr int P = (K - 1) / 2;
    __shared__ float wl[COUT * CIN * K * K];
    for (int i = threadIdx.x; i < COUT * CIN * K * K; i += blockDim.x) wl[i] = wp[i];
    __syncthreads();

    int idx = blockIdx.x * blockDim.x + threadIdx.x;
    int HW = H * W;
    int total = B * HW;
    if (idx >= total) return;
    int w = idx % W;
    int h = (idx / W) % H;
    int b = idx / HW;

    float den[COUT], nom[COUT];
#pragma unroll
    for (int i = 0; i < COUT; ++i) { den[i] = 0.f; nom[i] = 0.f; }

    for (int ci = 0; ci < CIN; ++ci) {
        const Tin* cp = cin + (size_t)(b * CIN + ci) * HW;
        const Tin* xp = xin + (size_t)(b * CIN + ci) * HW;
        for (int kh = 0; kh < K; ++kh) {
            int ih = h + kh - P;
            if (ih < 0 || ih >= H) continue;
#pragma unroll
            for (int kw = 0; kw < K; ++kw) {
                int iw = w + kw - P;
                if (iw < 0 || iw >= W) continue;
                float cv = (float)cp[ih * W + iw];
                float xc = (float)xp[ih * W + iw] * cv;
                const float* wr = &wl[(ci * K + kh) * K + kw];
#pragma unroll
                for (int co = 0; co < COUT; ++co) {
                    float wv = wr[co * CIN * K * K];
                    den[co] = fmaf(wv, cv, den[co]);
                    nom[co] = fmaf(wv, xc, nom[co]);
                }
            }
        }
    }

    size_t opix = (size_t)b * COUT * HW + (size_t)h * W + w;
#pragma unroll
    for (int co = 0; co < COUT; ++co) {
        float d = den[co];
        xout[opix + (size_t)co * HW] = (Tout)(nom[co] / (d + EPSV) + bias[co]);
        cout[opix + (size_t)co * HW] = (Tout)(d / ssum[co]);
    }
}

// ---------------------------------------------------------------------------
// Pool-gather: 2x2 argmax of c (first occurrence, order (0,0),(0,1),(1,0),(1,1)),
// gather x, c_out = cmax/4. H,W are INPUT dims.
// ---------------------------------------------------------------------------
template <typename T>
__global__ void __launch_bounds__(256) pool_gather(
    const T* __restrict__ x, const T* __restrict__ c,
    T* __restrict__ xo, T* __restrict__ co_,
    int BC, int H, int W) {
    int H2 = H >> 1, W2 = W >> 1;
    int idx = blockIdx.x * blockDim.x + threadIdx.x;
    int total = BC * H2 * W2;
    if (idx >= total) return;
    int wo = idx % W2;
    int ho = (idx / W2) % H2;
    int bc = idx / (W2 * H2);
    size_t base = (size_t)bc * H * W + (size_t)(2 * ho) * W + 2 * wo;
    float c00 = (float)c[base], c01 = (float)c[base + 1];
    float c10 = (float)c[base + W], c11 = (float)c[base + W + 1];
    int best = 0;
    float cb = c00;
    if (c01 > cb) { cb = c01; best = 1; }
    if (c10 > cb) { cb = c10; best = 2; }
    if (c11 > cb) { cb = c11; best = 3; }
    T xv = (best == 0) ? x[base] : (best == 1) ? x[base + 1]
         : (best == 2) ? x[base + W] : x[base + W + 1];
    xo[idx] = xv;
    co_[idx] = (T)(cb * 0.25f);
}

// ---------------------------------------------------------------------------
// Decoder nconv: concat of two 8-ch sources (src0 = ch 0-7, src1 = ch 8-15),
// source read at (h>>shift, w>>shift) (shift=1 == nearest 2x upsample).
// 3x3 pad=1, 16 -> 8 channels. FUSE7: apply final 1x1 nconv, 1-ch output.
// ---------------------------------------------------------------------------
template <typename T, typename Tout, bool FUSE7>
__global__ void __launch_bounds__(256) nconv_dec(
    const T* __restrict__ x0s, const T* __restrict__ c0s, int sh0,
    const T* __restrict__ x1s, const T* __restrict__ c1s, int sh1,
    const float* __restrict__ wp, const float* __restrict__ ssum,
    const float* __restrict__ bias,
    const float* __restrict__ wp7, const float* __restrict__ s7,
    const float* __restrict__ b7,
    Tout* __restrict__ xout, Tout* __restrict__ cout,
    int B, int H, int W) {
    constexpr int K = 3, P = 1, CIN = 16, COUT = 8;
    __shared__ float wl[COUT * CIN * K * K];  // 1152
    for (int i = threadIdx.x; i < COUT * CIN * K * K; i += blockDim.x) wl[i] = wp[i];
    __syncthreads();

    int idx = blockIdx.x * blockDim.x + threadIdx.x;
    int HW = H * W;
    int total = B * HW;
    if (idx >= total) return;
    int w = idx % W;
    int h = (idx / W) % H;
    int b = idx / HW;

    float den[COUT], nom[COUT];
#pragma unroll
    for (int i = 0; i < COUT; ++i) { den[i] = 0.f; nom[i] = 0.f; }

    for (int half = 0; half < 2; ++half) {
        const T* xs = half ? x1s : x0s;
        const T* cs = half ? c1s : c0s;
        int sh = half ? sh1 : sh0;
        int Hs = H >> sh, Ws = W >> sh;
        int HWs = Hs * Ws;
        for (int ci = 0; ci < 8; ++ci) {
            const T* cp = cs + (size_t)(b * 8 + ci) * HWs;
            const T* xp = xs + (size_t)(b * 8 + ci) * HWs;
            for (int kh = 0; kh < K; ++kh) {
                int ih = h + kh - P;
                if (ih < 0 || ih >= H) continue;
                int ihs = ih >> sh;
#pragma unroll
                for (int kw = 0; kw < K; ++kw) {
                    int iw = w + kw - P;
                    if (iw < 0 || iw >= W) continue;
                    int iws = iw >> sh;
                    float cv = (float)cp[ihs * Ws + iws];
                    float xc = (float)xp[ihs * Ws + iws] * cv;
                    const float* wr = &wl[((half * 8 + ci) * K + kh) * K + kw];
#pragma unroll
                    for (int co = 0; co < COUT; ++co) {
                        float wv = wr[co * CIN * K * K];
                        den[co] = fmaf(wv, cv, den[co]);
                        nom[co] = fmaf(wv, xc, nom[co]);
                    }
                }
            }
        }
    }

    if (FUSE7) {
        float den7 = 0.f, nom7 = 0.f;
#pragma unroll
        for (int co = 0; co < COUT; ++co) {
            float o = nom[co] / (den[co] + EPSV) + bias[co];
            float cc = den[co] / ssum[co];
            float wv = wp7[co];
            den7 = fmaf(wv, cc, den7);
            nom7 = fmaf(wv, o * cc, nom7);
        }
        size_t pix = (size_t)b * HW + (size_t)h * W + w;
        xout[pix] = (Tout)(nom7 / (den7 + EPSV) + b7[0]);
        cout[pix] = (Tout)(den7 / s7[0]);
    } else {
        size_t opix = (size_t)b * COUT * HW + (size_t)h * W + w;
#pragma unroll
        for (int co = 0; co < COUT; ++co) {
            float d = den[co];
            xout[opix + (size_t)co * HW] = (Tout)(nom[co] / (d + EPSV) + bias[co]);
            cout[opix + (size_t)co * HW] = (Tout)(d / ssum[co]);
        }
    }
}

// ---------------------------------------------------------------------------
// Full network with intermediates stored as T (fp32 or fp16), fp32 compute.
// ws layout (elements of T):
//   [0,F)      P0x   [F,2F)   P0c        (x1,c1 — persists to final decoder)
//   [2F,3F)    Ux / later D1x,D1c,D2x,D2c (4 x H2s = F)
//   [3F,4F)    Uc / later Q1..E2 (4Qs+4Es = 8.56M < F)
//   byte offset 4F*sizeof(T): WB, 6913 floats (softplus'd weights + sums)
// ---------------------------------------------------------------------------
template <typename T>
static void run_net(const float* x0, const float* c0,
                    const float* w1, const float* b1, const float* w2, const float* b2,
                    const float* w3, const float* b3, const float* w4, const float* b4,
                    const float* w5, const float* b5, const float* w6, const float* b6,
                    const float* w7, const float* b7,
                    float* outx, float* outc, void* d_ws, hipStream_t stream) {
    const int B = 8, H = 352, W = 1216;
    const int H2 = 176, W2 = 608, H4 = 88, W4 = 304, H8 = 44, W8 = 152;
    const size_t F   = (size_t)64 * H * W;    // 27,394,048 elements (8ch plane set)
    const size_t H2s = (size_t)64 * H2 * W2;
    const size_t Qs  = (size_t)64 * H4 * W4;
    const size_t Es  = (size_t)64 * H8 * W8;

    T* ws = (T*)d_ws;
    T* P0x = ws;
    T* P0c = ws + F;
    T* Ux  = ws + 2 * F;
    T* Uc  = ws + 3 * F;
    T* D1x = ws + 2 * F;
    T* D1c = D1x + H2s;
    T* D2x = D1c + H2s;
    T* D2c = D2x + H2s;
    T* Q1x = ws + 3 * F;
    T* Q1c = Q1x + Qs;
    T* Q2x = Q1c + Qs;
    T* Q2c = Q2x + Qs;
    T* E1x = Q2c + Qs;
    T* E1c = E1x + Es;
    T* E2x = E1c + Es;
    T* E2c = E2x + Es;
    float* WB = (float*)((char*)d_ws + 4 * F * sizeof(T));

    const float *wp1 = WB + 0,    *s1 = WB + 200;
    const float *wp2 = WB + 208,  *s2 = WB + 1808;
    const float *wp3 = WB + 1816, *s3 = WB + 3416;
    const float *wp4 = WB + 3424, *s4 = WB + 4576;
    const float *wp5 = WB + 4584, *s5 = WB + 5736;
    const float *wp6 = WB + 5744, *s6 = WB + 6896;
    const float *wp7 = WB + 6904, *s7 = WB + 6912;

    prep_weights<<<7, 256, 0, stream>>>(w1, w2, w3, w4, w5, w6, w7, WB);

    auto nb = [](size_t n) { return (int)((n + 255) / 256); };
    const size_t TF = (size_t)B * H * W;
    const size_t TH = (size_t)B * H2 * W2;
    const size_t TQ = (size_t)B * H4 * W4;
    const size_t TE = (size_t)B * H8 * W8;

    // Encoder: L1 -> P0, L2: P0 -> U, L3: U -> P0 (final x1,c1)
    nconv_enc<float, T, 1, 5><<<nb(TF), 256, 0, stream>>>(x0, c0, wp1, s1, b1, P0x, P0c, B, H, W);
    nconv_enc<T, T, 8, 5><<<nb(TF), 256, 0, stream>>>(P0x, P0c, wp2, s2, b2, Ux, Uc, B, H, W);
    nconv_enc<T, T, 8, 5><<<nb(TF), 256, 0, stream>>>(Ux, Uc, wp3, s3, b3, P0x, P0c, B, H, W);
    pool_gather<T><<<nb((size_t)64 * H2 * W2), 256, 0, stream>>>(P0x, P0c, D1x, D1c, 64, H, W);
    nconv_enc<T, T, 8, 5><<<nb(TH), 256, 0, stream>>>(D1x, D1c, wp2, s2, b2, D2x, D2c, B, H2, W2);
    nconv_enc<T, T, 8, 5><<<nb(TH), 256, 0, stream>>>(D2x, D2c, wp3, s3, b3, D1x, D1c, B, H2, W2);
    pool_gather<T><<<nb((size_t)64 * H4 * W4), 256, 0, stream>>>(D1x, D1c, Q1x, Q1c, 64, H2, W2);
    nconv_enc<T, T, 8, 5><<<nb(TQ), 256, 0, stream>>>(Q1x, Q1c, wp2, s2, b2, Q2x, Q2c, B, H4, W4);
    pool_gather<T><<<nb((size_t)64 * H8 * W8), 256, 0, stream>>>(Q2x, Q2c, E1x, E1c, 64, H4, W4);
    nconv_enc<T, T, 8, 5><<<nb(TE), 256, 0, stream>>>(E1x, E1c, wp2, s2, b2, E2x, E2c, B, H8, W8);

    // Decoder (up2+concat fused via per-source shift)
    nconv_dec<T, T, false><<<nb(TQ), 256, 0, stream>>>(
        Q2x, Q2c, 0, E2x, E2c, 1, wp4, s4, b4,
        (const float*)nullptr, (const float*)nullptr, (const float*)nullptr,
        Q1x, Q1c, B, H4, W4);
    nconv_dec<T, T, false><<<nb(TH), 256, 0, stream>>>(
        D1x, D1c, 0, Q1x, Q1c, 1, wp5, s5, b5,
        (const float*)nullptr, (const float*)nullptr, (const float*)nullptr,
        D2x, D2c, B, H2, W2);
    nconv_dec<T, float, true><<<nb(TF), 256, 0, stream>>>(
        D2x, D2c, 1, P0x, P0c, 0, wp6, s6, b6,
        wp7, s7, b7,
        outx, outc, B, H, W);
}

// ---------------------------------------------------------------------------
extern "C" void kernel_launch(void* const* d_in, const int* in_sizes, int n_in,
                              void* d_out, int out_size, void* d_ws, size_t ws_size,
                              hipStream_t stream) {
    const float* x0 = (const float*)d_in[0];
    const float* c0 = (const float*)d_in[1];
    const float* w1 = (const float*)d_in[2];
    const float* b1 = (const float*)d_in[3];
    const float* w2 = (const float*)d_in[4];
    const float* b2 = (const float*)d_in[5];
    const float* w3 = (const float*)d_in[6];
    const float* b3 = (const float*)d_in[7];
    const float* w4 = (const float*)d_in[8];
    const float* b4 = (const float*)d_in[9];
    const float* w5 = (const float*)d_in[10];
    const float* b5 = (const float*)d_in[11];
    const float* w6 = (const float*)d_in[12];
    const float* b6 = (const float*)d_in[13];
    const float* w7 = (const float*)d_in[14];
    const float* b7 = (const float*)d_in[15];

    const int B = 8, H = 352, W = 1216;
    const size_t F = (size_t)64 * H * W;  // 27,394,048
    float* outx = (float*)d_out;
    float* outc = outx + (size_t)B * H * W;

    const size_t needA = 4 * F * sizeof(float) + 7168 * sizeof(float);
    const size_t needH = 4 * F * sizeof(f16) + 7168 * sizeof(float);

    if (ws_size >= needA) {
        run_net<float>(x0, c0, w1, b1, w2, b2, w3, b3, w4, b4, w5, b5, w6, b6,
                       w7, b7, outx, outc, d_ws, stream);
    } else if (ws_size >= needH) {
        run_net<f16>(x0, c0, w1, b1, w2, b2, w3, b3, w4, b4, w5, b5, w6, b6,
                     w7, b7, outx, outc, d_ws, stream);
    }
    // else: ws too small for any layout — launch nothing (fails validation
    // with absmax == max|ref| ~ 0.57, a distinct signature from OOB-hang).
}

// Round 3
// 2320.542 us; speedup vs baseline: 1.1636x; 1.1636x over previous
//
#include <hip/hip_runtime.h>
#include <cmath>

#define EPSV 1e-20f

typedef _Float16 f16;
typedef _Float16 f16x2 __attribute__((ext_vector_type(2)));
typedef _Float16 h4 __attribute__((ext_vector_type(4)));
typedef float f32x2 __attribute__((ext_vector_type(2)));

__device__ __forceinline__ float softplusf(float x) {
    return fmaxf(x, 0.f) + log1pf(expf(-fabsf(x)));
}

// ---------------------------------------------------------------------------
// Weight prep: wp = softplus(w_raw), s[co] = sum over (ci,kh,kw). OIHW layout.
// wp1@0(200) s1@200(8) wp2@208(1600) s2@1808(8) wp3@1816(1600) s3@3416(8)
// wp4@3424(1152) s4@4576(8) wp5@4584(1152) s5@5736(8) wp6@5744(1152) s6@6896(8)
// wp7@6904(8) s7@6912(1)
// ---------------------------------------------------------------------------
__global__ void prep_weights(const float* __restrict__ w1, const float* __restrict__ w2,
                             const float* __restrict__ w3, const float* __restrict__ w4,
                             const float* __restrict__ w5, const float* __restrict__ w6,
                             const float* __restrict__ w7, float* __restrict__ wsw) {
    __shared__ float lds[1600];
    const float* srcs[7] = {w1, w2, w3, w4, w5, w6, w7};
    const int ns[7]    = {200, 1600, 1600, 1152, 1152, 1152, 8};
    const int pers[7]  = {25, 200, 200, 144, 144, 144, 8};
    const int couts[7] = {8, 8, 8, 8, 8, 8, 1};
    const int offs[7]  = {0, 208, 1816, 3424, 4584, 5744, 6904};
    const int soffs[7] = {200, 1808, 3416, 4576, 5736, 6896, 6912};

    int t = blockIdx.x;
    const float* src = srcs[t];
    int n = ns[t];
    for (int i = threadIdx.x; i < n; i += blockDim.x) {
        float v = softplusf(src[i]);
        lds[i] = v;
        wsw[offs[t] + i] = v;
    }
    __syncthreads();
    int per = pers[t];
    if ((int)threadIdx.x < couts[t]) {
        float s = 0.f;
        for (int i = 0; i < per; ++i) s += lds[threadIdx.x * per + i];
        wsw[soffs[t] + threadIdx.x] = s;
    }
}

// ---------------------------------------------------------------------------
// Row-segment loaders (zero for OOB columns). c0 is even; f16x2 loads 4B-aligned.
// ---------------------------------------------------------------------------
__device__ __forceinline__ void load_row8_h(const f16* __restrict__ row, int c0, int W,
                                            float v[8]) {
    if (c0 >= 0 && c0 + 8 <= W) {
#pragma unroll
        for (int i = 0; i < 4; ++i) {
            f16x2 t = *(const f16x2*)(row + c0 + 2 * i);
            v[2 * i] = (float)t[0];
            v[2 * i + 1] = (float)t[1];
        }
    } else {
#pragma unroll
        for (int i = 0; i < 8; ++i) {
            int c = c0 + i;
            v[i] = (c >= 0 && c < W) ? (float)row[c] : 0.f;
        }
    }
}

__device__ __forceinline__ void load_row6_h(const f16* __restrict__ row, int c0, int W,
                                            float v[6]) {
    if (c0 >= 0 && c0 + 6 <= W) {
#pragma unroll
        for (int i = 0; i < 3; ++i) {
            f16x2 t = *(const f16x2*)(row + c0 + 2 * i);
            v[2 * i] = (float)t[0];
            v[2 * i + 1] = (float)t[1];
        }
    } else {
#pragma unroll
        for (int i = 0; i < 6; ++i) {
            int c = c0 + i;
            v[i] = (c >= 0 && c < W) ? (float)row[c] : 0.f;
        }
    }
}

__device__ __forceinline__ void load_row8_f(const float* __restrict__ row, int c0, int W,
                                            float v[8]) {
    if (c0 >= 0 && c0 + 8 <= W) {
#pragma unroll
        for (int i = 0; i < 4; ++i) {
            f32x2 t = *(const f32x2*)(row + c0 + 2 * i);
            v[2 * i] = t[0];
            v[2 * i + 1] = t[1];
        }
    } else {
#pragma unroll
        for (int i = 0; i < 8; ++i) {
            int c = c0 + i;
            v[i] = (c >= 0 && c < W) ? row[c] : 0.f;
        }
    }
}

// ---------------------------------------------------------------------------
// Layer 1: fp32 (x, c) inputs (B,1,H,W) -> f16 (xc, c) 8-ch outputs. 5x5 pad 2.
// PX=4 pixels per thread along W.
// ---------------------------------------------------------------------------
__global__ void __launch_bounds__(256) nconv_l1(
    const float* __restrict__ x0, const float* __restrict__ c0,
    const float* __restrict__ wp, const float* __restrict__ ssum,
    const float* __restrict__ bias,
    f16* __restrict__ xcout, f16* __restrict__ cout,
    int B, int H, int W) {
    __shared__ __attribute__((aligned(16))) float wl[200];  // [kh][kw][co]
    for (int i = threadIdx.x; i < 200; i += 256) {
        int co = i & 7, r = i >> 3;  // r = kh*5+kw
        wl[i] = wp[co * 25 + r];
    }
    __syncthreads();

    const int Wq = W >> 2;
    int idx = blockIdx.x * 256 + threadIdx.x;
    int total = B * H * Wq;
    if (idx >= total) return;
    int w0 = (idx % Wq) << 2;
    int h = (idx / Wq) % H;
    int b = idx / (Wq * H);
    const int HW = H * W;

    float den[4][8] = {}, nom[4][8] = {};
    const float* cp = c0 + (size_t)b * HW;
    const float* xp = x0 + (size_t)b * HW;

    for (int kh = 0; kh < 5; ++kh) {
        int ih = h + kh - 2;
        if (ih < 0 || ih >= H) continue;
        float cv[8], xr[8], xv[8];
        load_row8_f(cp + (size_t)ih * W, w0 - 2, W, cv);
        load_row8_f(xp + (size_t)ih * W, w0 - 2, W, xr);
#pragma unroll
        for (int i = 0; i < 8; ++i) xv[i] = xr[i] * cv[i];
        const float* wrow = &wl[kh * 5 * 8];
#pragma unroll
        for (int kw = 0; kw < 5; ++kw) {
            const float4* wq = (const float4*)&wrow[kw * 8];
            float4 wa = wq[0], wb = wq[1];
            float wv[8] = {wa.x, wa.y, wa.z, wa.w, wb.x, wb.y, wb.z, wb.w};
#pragma unroll
            for (int co = 0; co < 8; ++co)
#pragma unroll
                for (int p = 0; p < 4; ++p) {
                    den[p][co] = fmaf(wv[co], cv[p + kw], den[p][co]);
                    nom[p][co] = fmaf(wv[co], xv[p + kw], nom[p][co]);
                }
        }
    }

    size_t obase = (size_t)b * 8 * HW + (size_t)h * W + w0;
#pragma unroll
    for (int co = 0; co < 8; ++co) {
        float ss = ssum[co], bb = bias[co];
        h4 xo, cc;
#pragma unroll
        for (int p = 0; p < 4; ++p) {
            float d = den[p][co];
            float c = d / ss;
            float x = nom[p][co] / (d + EPSV) + bb;
            xo[p] = (f16)(x * c);
            cc[p] = (f16)c;
        }
        *(h4*)(xcout + obase + (size_t)co * HW) = xo;
        *(h4*)(cout + obase + (size_t)co * HW) = cc;
    }
}

// ---------------------------------------------------------------------------
// Encoder nconv: f16 (xc, c) 8-ch -> f16 (xc, c) 8-ch, 5x5 pad 2, PX=4.
// ---------------------------------------------------------------------------
template <int CIN>
__global__ void __launch_bounds__(256) nconv_enc5(
    const f16* __restrict__ xcin, const f16* __restrict__ cin,
    const float* __restrict__ wp, const float* __restrict__ ssum,
    const float* __restrict__ bias,
    f16* __restrict__ xcout, f16* __restrict__ cout,
    int B, int H, int W) {
    constexpr int NW = CIN * 25 * 8;
    __shared__ __attribute__((aligned(16))) float wl[NW];  // [ci][kh][kw][co]
    for (int i = threadIdx.x; i < NW; i += 256) {
        int co = i & 7, r = i >> 3;
        int ci = r / 25, rem = r % 25;
        wl[i] = wp[((co * CIN + ci) * 5 + rem / 5) * 5 + rem % 5];
    }
    __syncthreads();

    const int Wq = W >> 2;
    int idx = blockIdx.x * 256 + threadIdx.x;
    int total = B * H * Wq;
    if (idx >= total) return;
    int w0 = (idx % Wq) << 2;
    int h = (idx / Wq) % H;
    int b = idx / (Wq * H);
    const int HW = H * W;

    float den[4][8] = {}, nom[4][8] = {};

#pragma unroll 1
    for (int ci = 0; ci < CIN; ++ci) {
        const f16* cp = cin + (size_t)(b * CIN + ci) * HW;
        const f16* xp = xcin + (size_t)(b * CIN + ci) * HW;
        for (int kh = 0; kh < 5; ++kh) {
            int ih = h + kh - 2;
            if (ih < 0 || ih >= H) continue;
            float cv[8], xv[8];
            load_row8_h(cp + (size_t)ih * W, w0 - 2, W, cv);
            load_row8_h(xp + (size_t)ih * W, w0 - 2, W, xv);
            const float* wrow = &wl[(ci * 25 + kh * 5) * 8];
#pragma unroll
            for (int kw = 0; kw < 5; ++kw) {
                const float4* wq = (const float4*)&wrow[kw * 8];
                float4 wa = wq[0], wb = wq[1];
                float wv[8] = {wa.x, wa.y, wa.z, wa.w, wb.x, wb.y, wb.z, wb.w};
#pragma unroll
                for (int co = 0; co < 8; ++co)
#pragma unroll
                    for (int p = 0; p < 4; ++p) {
                        den[p][co] = fmaf(wv[co], cv[p + kw], den[p][co]);
                        nom[p][co] = fmaf(wv[co], xv[p + kw], nom[p][co]);
                    }
            }
        }
    }

    size_t obase = (size_t)b * 8 * HW + (size_t)h * W + w0;
#pragma unroll
    for (int co = 0; co < 8; ++co) {
        float ss = ssum[co], bb = bias[co];
        h4 xo, cc;
#pragma unroll
        for (int p = 0; p < 4; ++p) {
            float d = den[p][co];
            float c = d / ss;
            float x = nom[p][co] / (d + EPSV) + bb;
            xo[p] = (f16)(x * c);
            cc[p] = (f16)c;
        }
        *(h4*)(xcout + obase + (size_t)co * HW) = xo;
        *(h4*)(cout + obase + (size_t)co * HW) = cc;
    }
}

// ---------------------------------------------------------------------------
// Pool-gather on (xc, c) planes: 2x2 argmax of c (first occurrence in order
// (0,0),(0,1),(1,0),(1,1)); out xc = xc[argmax]/4, out c = cmax/4.
// ---------------------------------------------------------------------------
__global__ void __launch_bounds__(256) pool_gather(
    const f16* __restrict__ xc, const f16* __restrict__ c,
    f16* __restrict__ xo, f16* __restrict__ co_,
    int BC, int H, int W) {
    int H2 = H >> 1, W2 = W >> 1;
    int idx = blockIdx.x * blockDim.x + threadIdx.x;
    int total = BC * H2 * W2;
    if (idx >= total) return;
    int wo = idx % W2;
    int ho = (idx / W2) % H2;
    int bc = idx / (W2 * H2);
    size_t base = (size_t)bc * H * W + (size_t)(2 * ho) * W + 2 * wo;
    f16x2 ca = *(const f16x2*)(c + base);
    f16x2 cb = *(const f16x2*)(c + base + W);
    f16x2 xa = *(const f16x2*)(xc + base);
    f16x2 xb = *(const f16x2*)(xc + base + W);
    float c00 = (float)ca[0], c01 = (float)ca[1];
    float c10 = (float)cb[0], c11 = (float)cb[1];
    float x00 = (float)xa[0], x01 = (float)xa[1];
    float x10 = (float)xb[0], x11 = (float)xb[1];
    float cbv = c00, xv = x00;
    if (c01 > cbv) { cbv = c01; xv = x01; }
    if (c10 > cbv) { cbv = c10; xv = x10; }
    if (c11 > cbv) { cbv = c11; xv = x11; }
    xo[idx] = (f16)(xv * 0.25f);
    co_[idx] = (f16)(cbv * 0.25f);
}

// ---------------------------------------------------------------------------
// Decoder half: accumulate one 8-ch source, 3x3 pad 1, source sampled at
// (h>>SH, w>>SH). PX=4. Column index j is compile-time per (p,kw).
// ---------------------------------------------------------------------------
template <int SH>
__device__ __forceinline__ void dec_half(
    const f16* __restrict__ xcs, const f16* __restrict__ cs,
    int b, int h, int w0, int H, int W,
    const float* wl, int cibase, float den[4][8], float nom[4][8]) {
    const int Hs = H >> SH, Ws = W >> SH;
    const int HWs = Hs * Ws;
#pragma unroll 1
    for (int ci = 0; ci < 8; ++ci) {
        const f16* cp = cs + (size_t)(b * 8 + ci) * HWs;
        const f16* xp = xcs + (size_t)(b * 8 + ci) * HWs;
        for (int kh = 0; kh < 3; ++kh) {
            int ih = h + kh - 1;
            if (ih < 0 || ih >= H) continue;
            int ihs = ih >> SH;
            float cv[8], xv[8];
            if (SH == 0) {
                load_row8_h(cp + (size_t)ihs * Ws, w0 - 2, Ws, cv);
                load_row8_h(xp + (size_t)ihs * Ws, w0 - 2, Ws, xv);
            } else {
                load_row6_h(cp + (size_t)ihs * Ws, (w0 >> 1) - 2, Ws, cv);
                load_row6_h(xp + (size_t)ihs * Ws, (w0 >> 1) - 2, Ws, xv);
            }
            const float* wrow = &wl[((cibase + ci) * 9 + kh * 3) * 8];
#pragma unroll
            for (int kw = 0; kw < 3; ++kw) {
                const float4* wq = (const float4*)&wrow[kw * 8];
                float4 wa = wq[0], wb = wq[1];
                float wv[8] = {wa.x, wa.y, wa.z, wa.w, wb.x, wb.y, wb.z, wb.w};
#pragma unroll
                for (int co = 0; co < 8; ++co)
#pragma unroll
                    for (int p = 0; p < 4; ++p) {
                        const int j = (SH == 0) ? (p + kw + 1)
                                                : (2 + ((p + kw - 1) >> 1));
                        den[p][co] = fmaf(wv[co], cv[j], den[p][co]);
                        nom[p][co] = fmaf(wv[co], xv[j], nom[p][co]);
                    }
            }
        }
    }
}

// ---------------------------------------------------------------------------
// Decoder nconv: concat(src0, src1) -> 8 ch, 3x3 pad 1.
// FUSE7: apply the final 1x1 nconv and write fp32 1-ch (xout, cout).
// ---------------------------------------------------------------------------
template <int SH0, int SH1, bool FUSE7>
__global__ void __launch_bounds__(256) nconv_dec3(
    const f16* __restrict__ xc0, const f16* __restrict__ c0s,
    const f16* __restrict__ xc1, const f16* __restrict__ c1s,
    const float* __restrict__ wp, const float* __restrict__ ssum,
    const float* __restrict__ bias,
    const float* __restrict__ wp7, const float* __restrict__ s7,
    const float* __restrict__ b7,
    f16* __restrict__ xcout, f16* __restrict__ ccout,
    float* __restrict__ xoutf, float* __restrict__ coutf,
    int B, int H, int W) {
    __shared__ __attribute__((aligned(16))) float wl[1152];  // [ci16][kh][kw][co]
    for (int i = threadIdx.x; i < 1152; i += 256) {
        int co = i & 7, r = i >> 3;
        int ci = r / 9, rem = r % 9;
        wl[i] = wp[((co * 16 + ci) * 3 + rem / 3) * 3 + rem % 3];
    }
    __syncthreads();

    const int Wq = W >> 2;
    int idx = blockIdx.x * 256 + threadIdx.x;
    int total = B * H * Wq;
    if (idx >= total) return;
    int w0 = (idx % Wq) << 2;
    int h = (idx / Wq) % H;
    int b = idx / (Wq * H);
    const int HW = H * W;

    float den[4][8] = {}, nom[4][8] = {};
    dec_half<SH0>(xc0, c0s, b, h, w0, H, W, wl, 0, den, nom);
    dec_half<SH1>(xc1, c1s, b, h, w0, H, W, wl, 8, den, nom);

    if (FUSE7) {
        float ox[4], oc[4];
#pragma unroll
        for (int p = 0; p < 4; ++p) {
            float den7 = 0.f, nom7 = 0.f;
#pragma unroll
            for (int co = 0; co < 8; ++co) {
                float d = den[p][co];
                float o = nom[p][co] / (d + EPSV) + bias[co];
                float cc = d / ssum[co];
                float wv = wp7[co];
                den7 = fmaf(wv, cc, den7);
                nom7 = fmaf(wv, o * cc, nom7);
            }
            ox[p] = nom7 / (den7 + EPSV) + b7[0];
            oc[p] = den7 / s7[0];
        }
        size_t pix = (size_t)b * HW + (size_t)h * W + w0;
        *(float4*)(xoutf + pix) = make_float4(ox[0], ox[1], ox[2], ox[3]);
        *(float4*)(coutf + pix) = make_float4(oc[0], oc[1], oc[2], oc[3]);
    } else {
        size_t obase = (size_t)b * 8 * HW + (size_t)h * W + w0;
#pragma unroll
        for (int co = 0; co < 8; ++co) {
            float ss = ssum[co], bb = bias[co];
            h4 xo, cc;
#pragma unroll
            for (int p = 0; p < 4; ++p) {
                float d = den[p][co];
                float c = d / ss;
                float x = nom[p][co] / (d + EPSV) + bb;
                xo[p] = (f16)(x * c);
                cc[p] = (f16)c;
            }
            *(h4*)(xcout + obase + (size_t)co * HW) = xo;
            *(h4*)(ccout + obase + (size_t)co * HW) = cc;
        }
    }
}

// ---------------------------------------------------------------------------
extern "C" void kernel_launch(void* const* d_in, const int* in_sizes, int n_in,
                              void* d_out, int out_size, void* d_ws, size_t ws_size,
                              hipStream_t stream) {
    const float* x0 = (const float*)d_in[0];
    const float* c0 = (const float*)d_in[1];
    const float* w1 = (const float*)d_in[2];
    const float* b1 = (const float*)d_in[3];
    const float* w2 = (const float*)d_in[4];
    const float* b2 = (const float*)d_in[5];
    const float* w3 = (const float*)d_in[6];
    const float* b3 = (const float*)d_in[7];
    const float* w4 = (const float*)d_in[8];
    const float* b4 = (const float*)d_in[9];
    const float* w5 = (const float*)d_in[10];
    const float* b5 = (const float*)d_in[11];
    const float* w6 = (const float*)d_in[12];
    const float* b6 = (const float*)d_in[13];
    const float* w7 = (const float*)d_in[14];
    const float* b7 = (const float*)d_in[15];

    const int B = 8, H = 352, W = 1216;
    const int H2 = 176, W2 = 608, H4 = 88, W4 = 304, H8 = 44, W8 = 152;
    const size_t F   = (size_t)64 * H * W;
    const size_t H2s = (size_t)64 * H2 * W2;
    const size_t Qs  = (size_t)64 * H4 * W4;
    const size_t Es  = (size_t)64 * H8 * W8;

    const size_t needH = 4 * F * sizeof(f16) + 7168 * sizeof(float);
    if (ws_size < needH) return;  // distinct fast-fail signature

    f16* ws = (f16*)d_ws;
    f16* P0x = ws;            // full-res (xc, c) — persists to final decoder
    f16* P0c = ws + F;
    f16* Ux  = ws + 2 * F;    // full-res ping buffer
    f16* Uc  = ws + 3 * F;
    f16* D1x = ws + 2 * F;    // half-res set reuses region 2
    f16* D1c = D1x + H2s;
    f16* D2x = D1c + H2s;
    f16* D2c = D2x + H2s;
    f16* Q1x = ws + 3 * F;    // quarter + eighth reuse region 3
    f16* Q1c = Q1x + Qs;
    f16* Q2x = Q1c + Qs;
    f16* Q2c = Q2x + Qs;
    f16* E1x = Q2c + Qs;
    f16* E1c = E1x + Es;
    f16* E2x = E1c + Es;
    f16* E2c = E2x + Es;
    float* WB = (float*)((char*)d_ws + 4 * F * sizeof(f16));

    const float *wp1 = WB + 0,    *s1 = WB + 200;
    const float *wp2 = WB + 208,  *s2 = WB + 1808;
    const float *wp3 = WB + 1816, *s3 = WB + 3416;
    const float *wp4 = WB + 3424, *s4 = WB + 4576;
    const float *wp5 = WB + 4584, *s5 = WB + 5736;
    const float *wp6 = WB + 5744, *s6 = WB + 6896;
    const float *wp7 = WB + 6904, *s7 = WB + 6912;

    prep_weights<<<7, 256, 0, stream>>>(w1, w2, w3, w4, w5, w6, w7, WB);

    auto nb = [](size_t n) { return (int)((n + 255) / 256); };
    const size_t TF = (size_t)B * H * (W / 4);
    const size_t TH = (size_t)B * H2 * (W2 / 4);
    const size_t TQ = (size_t)B * H4 * (W4 / 4);
    const size_t TE = (size_t)B * H8 * (W8 / 4);

    // Encoder
    nconv_l1<<<nb(TF), 256, 0, stream>>>(x0, c0, wp1, s1, b1, P0x, P0c, B, H, W);
    nconv_enc5<8><<<nb(TF), 256, 0, stream>>>(P0x, P0c, wp2, s2, b2, Ux, Uc, B, H, W);
    nconv_enc5<8><<<nb(TF), 256, 0, stream>>>(Ux, Uc, wp3, s3, b3, P0x, P0c, B, H, W);
    pool_gather<<<nb((size_t)64 * H2 * W2), 256, 0, stream>>>(P0x, P0c, D1x, D1c, 64, H, W);
    nconv_enc5<8><<<nb(TH), 256, 0, stream>>>(D1x, D1c, wp2, s2, b2, D2x, D2c, B, H2, W2);
    nconv_enc5<8><<<nb(TH), 256, 0, stream>>>(D2x, D2c, wp3, s3, b3, D1x, D1c, B, H2, W2);
    pool_gather<<<nb((size_t)64 * H4 * W4), 256, 0, stream>>>(D1x, D1c, Q1x, Q1c, 64, H2, W2);
    nconv_enc5<8><<<nb(TQ), 256, 0, stream>>>(Q1x, Q1c, wp2, s2, b2, Q2x, Q2c, B, H4, W4);
    pool_gather<<<nb((size_t)64 * H8 * W8), 256, 0, stream>>>(Q2x, Q2c, E1x, E1c, 64, H4, W4);
    nconv_enc5<8><<<nb(TE), 256, 0, stream>>>(E1x, E1c, wp2, s2, b2, E2x, E2c, B, H8, W8);

    // Decoder (up2 + concat fused via per-source shift)
    nconv_dec3<0, 1, false><<<nb(TQ), 256, 0, stream>>>(
        Q2x, Q2c, E2x, E2c, wp4, s4, b4,
        (const float*)nullptr, (const float*)nullptr, (const float*)nullptr,
        Q1x, Q1c, (float*)nullptr, (float*)nullptr, B, H4, W4);
    nconv_dec3<0, 1, false><<<nb(TH), 256, 0, stream>>>(
        D1x, D1c, Q1x, Q1c, wp5, s5, b5,
        (const float*)nullptr, (const float*)nullptr, (const float*)nullptr,
        D2x, D2c, (float*)nullptr, (float*)nullptr, B, H2, W2);

    float* outx = (float*)d_out;
    float* outc = outx + (size_t)B * H * W;
    nconv_dec3<1, 0, true><<<nb(TF), 256, 0, stream>>>(
        D2x, D2c, P0x, P0c, wp6, s6, b6,
        wp7, s7, b7,
        (f16*)nullptr, (f16*)nullptr, outx, outc, B, H, W);
}

// Round 4
// 740.156 us; speedup vs baseline: 3.6480x; 3.1352x over previous
//
#include <hip/hip_runtime.h>
#include <cmath>

#define EPSV 1e-20f

typedef _Float16 f16;
typedef _Float16 v8h __attribute__((ext_vector_type(8)));
typedef float v4f __attribute__((ext_vector_type(4)));
typedef float f32x2 __attribute__((ext_vector_type(2)));

__device__ __forceinline__ float softplusf(float x) {
    return fmaxf(x, 0.f) + log1pf(expf(-fabsf(x)));
}

__device__ __forceinline__ v8h v8h_zero() {
    v8h z = {0, 0, 0, 0, 0, 0, 0, 0};
    return z;
}

// ---------------------------------------------------------------------------
// WT float layout (at byte offset 4F*2 in ws):
//   wp1 @ [0..199]  (softplus'd 5x5x1x8, OIHW)
//   s_l @ [200 + (l-1)*8]  l=1..7  (per-co kernel sums; s7 is 1 value @248)
//   wp7 @ [256..263]
// BF2 (f16, 7*64*8) @ byte +2048 ; BF3 @ byte +9216
// ---------------------------------------------------------------------------
__global__ void prep_scalars(const float* __restrict__ w1, const float* __restrict__ w2,
                             const float* __restrict__ w3, const float* __restrict__ w4,
                             const float* __restrict__ w5, const float* __restrict__ w6,
                             const float* __restrict__ w7, float* __restrict__ WT) {
    __shared__ float lds[1600];
    const float* srcs[7] = {w1, w2, w3, w4, w5, w6, w7};
    const int ns[7]    = {200, 1600, 1600, 1152, 1152, 1152, 8};
    const int pers[7]  = {25, 200, 200, 144, 144, 144, 8};
    const int couts[7] = {8, 8, 8, 8, 8, 8, 1};
    int t = blockIdx.x;
    const float* src = srcs[t];
    int n = ns[t];
    for (int i = threadIdx.x; i < n; i += blockDim.x) {
        float v = softplusf(src[i]);
        lds[i] = v;
        if (t == 0) WT[i] = v;        // wp1
        if (t == 6) WT[256 + i] = v;  // wp7
    }
    __syncthreads();
    if ((int)threadIdx.x < couts[t]) {
        float s = 0.f;
        int per = pers[t];
        for (int i = 0; i < per; ++i) s += lds[threadIdx.x * per + i];
        WT[200 + t * 8 + threadIdx.x] = s;
    }
}

// B-fragment pack, encoder 5x5 8ci: k-pos (sub=lane>>4, j) == tap g*4+sub, ci j.
__global__ void pack_enc_frag(const float* __restrict__ w2, const float* __restrict__ w3,
                              f16* __restrict__ dst2, f16* __restrict__ dst3) {
    const float* w = blockIdx.x ? w3 : w2;
    f16* dst = blockIdx.x ? dst3 : dst2;
    for (int i = threadIdx.x; i < 7 * 64 * 8; i += blockDim.x) {
        int g = i >> 9;
        int l = (i >> 3) & 63;
        int j = i & 7;
        int co = l & 15, sub = l >> 4;
        int t = g * 4 + sub;
        float v = 0.f;
        if (co < 8 && t <= 24) {
            v = softplusf(w[((co * 8 + j) * 5 + t / 5) * 5 + t % 5]);
        }
        dst[i] = (f16)v;
    }
}

// B-fragment pack, decoder 3x3 16ci: groups 0-2 = src0(ci 0-7), 3-5 = src1(ci 8-15).
__global__ void pack_dec_frag(const float* __restrict__ w4, const float* __restrict__ w5,
                              const float* __restrict__ w6,
                              f16* __restrict__ dst4, f16* __restrict__ dst5,
                              f16* __restrict__ dst6) {
    const float* ww[3] = {w4, w5, w6};
    f16* dd[3] = {dst4, dst5, dst6};
    const float* w = ww[blockIdx.x];
    f16* dst = dd[blockIdx.x];
    for (int i = threadIdx.x; i < 6 * 64 * 8; i += blockDim.x) {
        int g = i >> 9;
        int l = (i >> 3) & 63;
        int j = i & 7;
        int co = l & 15, sub = l >> 4;
        int srcsel = g / 3, gs = g % 3;
        int t = gs * 4 + sub;
        float v = 0.f;
        if (co < 8 && t <= 8) {
            int ci = srcsel * 8 + j;
            v = softplusf(w[((co * 16 + ci) * 3 + t / 3) * 3 + t % 3]);
        }
        dst[i] = (f16)v;
    }
}

// ---------------------------------------------------------------------------
// fp32 row loader (L1 only)
// ---------------------------------------------------------------------------
__device__ __forceinline__ void load_row8_f(const float* __restrict__ row, int c0, int W,
                                            float v[8]) {
    if (c0 >= 0 && c0 + 8 <= W) {
#pragma unroll
        for (int i = 0; i < 4; ++i) {
            f32x2 t = *(const f32x2*)(row + c0 + 2 * i);
            v[2 * i] = t[0];
            v[2 * i + 1] = t[1];
        }
    } else {
#pragma unroll
        for (int i = 0; i < 8; ++i) {
            int c = c0 + i;
            v[i] = (c >= 0 && c < W) ? row[c] : 0.f;
        }
    }
}

// ---------------------------------------------------------------------------
// Layer 1 (CIN=1) VALU: fp32 planar (x,c) -> f16 NHWC (xc, c). 5x5 pad 2, PX=4.
// ---------------------------------------------------------------------------
__global__ void __launch_bounds__(256) nconv_l1(
    const float* __restrict__ x0, const float* __restrict__ c0,
    const float* __restrict__ wp, const float* __restrict__ ssum,
    const float* __restrict__ bias,
    f16* __restrict__ xcout, f16* __restrict__ cout,
    int B, int H, int W) {
    __shared__ __attribute__((aligned(16))) float wl[200];  // [kh][kw][co]
    for (int i = threadIdx.x; i < 200; i += 256) {
        int co = i & 7, r = i >> 3;
        wl[i] = wp[co * 25 + r];
    }
    __syncthreads();

    const int Wq = W >> 2;
    int idx = blockIdx.x * 256 + threadIdx.x;
    int total = B * H * Wq;
    if (idx >= total) return;
    int w0 = (idx % Wq) << 2;
    int h = (idx / Wq) % H;
    int b = idx / (Wq * H);
    const int HW = H * W;

    float den[4][8] = {}, nom[4][8] = {};
    const float* cp = c0 + (size_t)b * HW;
    const float* xp = x0 + (size_t)b * HW;

    for (int kh = 0; kh < 5; ++kh) {
        int ih = h + kh - 2;
        if (ih < 0 || ih >= H) continue;
        float cv[8], xr[8], xv[8];
        load_row8_f(cp + (size_t)ih * W, w0 - 2, W, cv);
        load_row8_f(xp + (size_t)ih * W, w0 - 2, W, xr);
#pragma unroll
        for (int i = 0; i < 8; ++i) xv[i] = xr[i] * cv[i];
        const float* wrow = &wl[kh * 5 * 8];
#pragma unroll
        for (int kw = 0; kw < 5; ++kw) {
            const float4* wq = (const float4*)&wrow[kw * 8];
            float4 wa = wq[0], wb = wq[1];
            float wv[8] = {wa.x, wa.y, wa.z, wa.w, wb.x, wb.y, wb.z, wb.w};
#pragma unroll
            for (int co = 0; co < 8; ++co)
#pragma unroll
                for (int p = 0; p < 4; ++p) {
                    den[p][co] = fmaf(wv[co], cv[p + kw], den[p][co]);
                    nom[p][co] = fmaf(wv[co], xv[p + kw], nom[p][co]);
                }
        }
    }

    float ssv[8], bbv[8];
#pragma unroll
    for (int co = 0; co < 8; ++co) { ssv[co] = ssum[co]; bbv[co] = bias[co]; }
    size_t pa = ((size_t)(b * H + h) * W + w0) * 8;
#pragma unroll
    for (int p = 0; p < 4; ++p) {
        v8h xc8, c8;
#pragma unroll
        for (int co = 0; co < 8; ++co) {
            float d = den[p][co];
            float cc = d / ssv[co];
            float xo = nom[p][co] / (d + EPSV) + bbv[co];
            xc8[co] = (f16)(xo * cc);
            c8[co] = (f16)cc;
        }
        *(v8h*)(xcout + pa + p * 8) = xc8;
        *(v8h*)(cout + pa + p * 8) = c8;
    }
}

// ---------------------------------------------------------------------------
// Pool-gather NHWC: 2x2 argmax of c per channel (first occurrence order
// (0,0),(0,1),(1,0),(1,1)); xc' = xc[argmax]/4, c' = cmax/4.
// ---------------------------------------------------------------------------
__global__ void __launch_bounds__(256) pool_nhwc(
    const f16* __restrict__ xc, const f16* __restrict__ c,
    f16* __restrict__ xo, f16* __restrict__ co_,
    int B, int H, int W) {
    int H2 = H >> 1, W2 = W >> 1;
    int idx = blockIdx.x * 256 + threadIdx.x;
    int total = B * H2 * W2;
    if (idx >= total) return;
    int wo = idx % W2;
    int ho = (idx / W2) % H2;
    int b = idx / (W2 * H2);
    unsigned base = (unsigned)(((b * H + 2 * ho) * W + 2 * wo) * 8);
    unsigned rb = (unsigned)(W * 8);
    v8h c00 = *(const v8h*)(c + base), c01 = *(const v8h*)(c + base + 8);
    v8h c10 = *(const v8h*)(c + base + rb), c11 = *(const v8h*)(c + base + rb + 8);
    v8h x00 = *(const v8h*)(xc + base), x01 = *(const v8h*)(xc + base + 8);
    v8h x10 = *(const v8h*)(xc + base + rb), x11 = *(const v8h*)(xc + base + rb + 8);
    v8h xr, cr;
#pragma unroll
    for (int e = 0; e < 8; ++e) {
        float b0 = (float)c00[e], b1 = (float)c01[e], b2 = (float)c10[e], b3 = (float)c11[e];
        float cb = b0;
        float xv = (float)x00[e];
        if (b1 > cb) { cb = b1; xv = (float)x01[e]; }
        if (b2 > cb) { cb = b2; xv = (float)x10[e]; }
        if (b3 > cb) { cb = b3; xv = (float)x11[e]; }
        xr[e] = (f16)(xv * 0.25f);
        cr[e] = (f16)(cb * 0.25f);
    }
    unsigned oa = (unsigned)(((b * H2 + ho) * W2 + wo) * 8);
    *(v8h*)(xo + oa) = xr;
    *(v8h*)(co_ + oa) = cr;
}

// ---------------------------------------------------------------------------
// Encoder nconv via MFMA: NHWC f16 (xc,c) 8ch -> 8ch, 5x5 pad 2.
// One wave per 16-pixel tile (grid-stride). K=32 packs 4 taps x 8 ci.
// ---------------------------------------------------------------------------
__global__ void __launch_bounds__(256) enc5_mfma(
    const f16* __restrict__ xcin, const f16* __restrict__ cin,
    const f16* __restrict__ bfrag, const float* __restrict__ ssum,
    const float* __restrict__ bias,
    f16* __restrict__ xcout, f16* __restrict__ cout,
    int B, int H, int W) {
    const int lane = threadIdx.x & 63;
    const int m = lane & 15, sub = lane >> 4;  // m: A-row (pixel) and C-col (co)
    v8h bf[7];
#pragma unroll
    for (int g = 0; g < 7; ++g)
        bf[g] = *(const v8h*)(bfrag + ((g << 6) + lane) * 8);
    int dh[7], dwv[7], offg[7];
#pragma unroll
    for (int g = 0; g < 7; ++g) {
        int t = g * 4 + sub;
        if (t > 24) t = 24;  // pad taps: address clamps to a real tap, weight is 0
        dh[g] = t / 5 - 2;
        dwv[g] = t % 5 - 2;
        offg[g] = (dh[g] * W + dwv[g]) * 8;
    }
    float ss = 1.f, bb = 0.f;
    if (m < 8) { ss = ssum[m]; bb = bias[m]; }
    const float rss = 1.f / ss;

    const int tilesW = (W + 15) >> 4;
    const int ntiles = B * H * tilesW;
    const int gwave = blockIdx.x * 4 + (threadIdx.x >> 6);
    const int nw = gridDim.x * 4;

    for (int t = gwave; t < ntiles; t += nw) {
        const int tw = t % tilesW;
        const int hb = t / tilesW;
        const int h = hb % H;
        const int b = hb / H;
        const int w0 = tw << 4;
        const int pixbase = ((b * H + h) * W + w0 + m) * 8;
        v4f accd = {0.f, 0.f, 0.f, 0.f}, accn = {0.f, 0.f, 0.f, 0.f};
        bool interior = (h >= 2) && (h + 2 < H) && (w0 >= 2) && (w0 + 17 < W);
        if (interior) {
#pragma unroll
            for (int g = 0; g < 7; ++g) {
                unsigned a = (unsigned)(pixbase + offg[g]);
                v8h ac = *(const v8h*)(cin + a);
                v8h ax = *(const v8h*)(xcin + a);
                accd = __builtin_amdgcn_mfma_f32_16x16x32_f16(ac, bf[g], accd, 0, 0, 0);
                accn = __builtin_amdgcn_mfma_f32_16x16x32_f16(ax, bf[g], accn, 0, 0, 0);
            }
        } else {
#pragma unroll
            for (int g = 0; g < 7; ++g) {
                int hh = h + dh[g], wwp = w0 + m + dwv[g];
                bool ok = (hh >= 0) && (hh < H) && (wwp >= 0) && (wwp < W);
                int hc = min(max(hh, 0), H - 1);
                int wc = min(max(wwp, 0), W - 1);
                unsigned a = (unsigned)(((b * H + hc) * W + wc) * 8);
                v8h ac = *(const v8h*)(cin + a);
                v8h ax = *(const v8h*)(xcin + a);
                if (!ok) { ac = v8h_zero(); ax = v8h_zero(); }
                accd = __builtin_amdgcn_mfma_f32_16x16x32_f16(ac, bf[g], accd, 0, 0, 0);
                accn = __builtin_amdgcn_mfma_f32_16x16x32_f16(ax, bf[g], accn, 0, 0, 0);
            }
        }
        if (m < 8) {  // m is the C-col = co for this lane
#pragma unroll
            for (int j = 0; j < 4; ++j) {
                int w = w0 + sub * 4 + j;  // C-row = pixel
                if (w < W) {
                    float d = accd[j];
                    float cc = d * rss;
                    float xo = accn[j] / (d + EPSV) + bb;
                    unsigned oa = (unsigned)(((b * H + h) * W + w) * 8 + m);
                    cout[oa] = (f16)cc;
                    xcout[oa] = (f16)(xo * cc);
                }
            }
        }
    }
}

// ---------------------------------------------------------------------------
// Decoder source accumulate: 3x3 pad 1, source sampled at (>>SH).
// ---------------------------------------------------------------------------
template <int SH>
__device__ __forceinline__ void dec_src_mfma(
    const f16* __restrict__ xcs, const f16* __restrict__ cs,
    int b, int h, int w0, int m, int H, int W,
    const int dh[3], const int dwv[3], const v8h* bf, int gbase,
    v4f& accd, v4f& accn) {
    const int Hs = H >> SH, Ws = W >> SH;
#pragma unroll
    for (int gs = 0; gs < 3; ++gs) {
        int hh = h + dh[gs], wwp = w0 + m + dwv[gs];
        bool ok = (hh >= 0) && (hh < H) && (wwp >= 0) && (wwp < W);
        int hc = min(max(hh, 0), H - 1);
        int wc = min(max(wwp, 0), W - 1);
        unsigned a = (unsigned)(((b * Hs + (hc >> SH)) * Ws + (wc >> SH)) * 8);
        v8h ac = *(const v8h*)(cs + a);
        v8h ax = *(const v8h*)(xcs + a);
        if (!ok) { ac = v8h_zero(); ax = v8h_zero(); }
        accd = __builtin_amdgcn_mfma_f32_16x16x32_f16(ac, bf[gbase + gs], accd, 0, 0, 0);
        accn = __builtin_amdgcn_mfma_f32_16x16x32_f16(ax, bf[gbase + gs], accn, 0, 0, 0);
    }
}

// ---------------------------------------------------------------------------
// Decoder nconv via MFMA: concat(src0, src1) 16ch -> 8ch, 3x3 pad 1.
// FUSE7: fused final 1x1 nconv, fp32 1-ch (x, c) outputs.
// ---------------------------------------------------------------------------
template <int SH0, int SH1, bool FUSE7>
__global__ void __launch_bounds__(256) dec3_mfma(
    const f16* __restrict__ xc0, const f16* __restrict__ c0p,
    const f16* __restrict__ xc1, const f16* __restrict__ c1p,
    const f16* __restrict__ bfrag,
    const float* __restrict__ ssum, const float* __restrict__ bias,
    const float* __restrict__ wp7, const float* __restrict__ s7p,
    const float* __restrict__ b7p,
    f16* __restrict__ xcout, f16* __restrict__ ccout,
    float* __restrict__ xoutf, float* __restrict__ coutf,
    int B, int H, int W) {
    const int lane = threadIdx.x & 63;
    const int m = lane & 15, sub = lane >> 4;
    v8h bf[6];
#pragma unroll
    for (int g = 0; g < 6; ++g)
        bf[g] = *(const v8h*)(bfrag + ((g << 6) + lane) * 8);
    int dh[3], dwv[3];
#pragma unroll
    for (int gs = 0; gs < 3; ++gs) {
        int t = gs * 4 + sub;
        if (t > 8) t = 8;
        dh[gs] = t / 3 - 1;
        dwv[gs] = t % 3 - 1;
    }
    float ss = 1.f, bb = 0.f, w7v = 0.f;
    if (m < 8) {
        ss = ssum[m];
        bb = bias[m];
        if (FUSE7) w7v = wp7[m];
    }
    const float rss = 1.f / ss;
    float rs7 = 0.f, b7v = 0.f;
    if (FUSE7) { rs7 = 1.f / s7p[0]; b7v = b7p[0]; }

    const int tilesW = W >> 4;
    const int ntiles = B * H * tilesW;
    const int gwave = blockIdx.x * 4 + (threadIdx.x >> 6);
    const int nw = gridDim.x * 4;

    for (int t = gwave; t < ntiles; t += nw) {
        const int tw = t % tilesW;
        const int hb = t / tilesW;
        const int h = hb % H;
        const int b = hb / H;
        const int w0 = tw << 4;
        v4f accd = {0.f, 0.f, 0.f, 0.f}, accn = {0.f, 0.f, 0.f, 0.f};
        dec_src_mfma<SH0>(xc0, c0p, b, h, w0, m, H, W, dh, dwv, bf, 0, accd, accn);
        dec_src_mfma<SH1>(xc1, c1p, b, h, w0, m, H, W, dh, dwv, bf, 3, accd, accn);

        if (FUSE7) {
            float td[4], tn[4];
#pragma unroll
            for (int j = 0; j < 4; ++j) {
                float d = accd[j];          // exactly 0 for co>=8 (B zero-padded)
                float cc = d * rss;
                float o = accn[j] / (d + EPSV) + bb;
                td[j] = w7v * cc;
                tn[j] = w7v * (o * cc);
            }
#pragma unroll
            for (int x = 1; x < 16; x <<= 1) {
#pragma unroll
                for (int j = 0; j < 4; ++j) {
                    td[j] += __shfl_xor(td[j], x);
                    tn[j] += __shfl_xor(tn[j], x);
                }
            }
            if (m < 2) {
                float4 out;
                float* v = &out.x;
#pragma unroll
                for (int j = 0; j < 4; ++j) {
                    float dv = td[j];
                    v[j] = (m == 0) ? (tn[j] / (dv + EPSV) + b7v) : (dv * rs7);
                }
                float* dst = (m == 0) ? xoutf : coutf;
                *(float4*)(dst + ((size_t)(b * H + h) * W + w0 + sub * 4)) = out;
            }
        } else {
            if (m < 8) {
#pragma unroll
                for (int j = 0; j < 4; ++j) {
                    int w = w0 + sub * 4 + j;
                    float d = accd[j];
                    float cc = d * rss;
                    float xo = accn[j] / (d + EPSV) + bb;
                    unsigned oa = (unsigned)(((b * H + h) * W + w) * 8 + m);
                    ccout[oa] = (f16)cc;
                    xcout[oa] = (f16)(xo * cc);
                }
            }
        }
    }
}

// ---------------------------------------------------------------------------
extern "C" void kernel_launch(void* const* d_in, const int* in_sizes, int n_in,
                              void* d_out, int out_size, void* d_ws, size_t ws_size,
                              hipStream_t stream) {
    const float* x0 = (const float*)d_in[0];
    const float* c0 = (const float*)d_in[1];
    const float* w1 = (const float*)d_in[2];
    const float* b1 = (const float*)d_in[3];
    const float* w2 = (const float*)d_in[4];
    const float* b2 = (const float*)d_in[5];
    const float* w3 = (const float*)d_in[6];
    const float* b3 = (const float*)d_in[7];
    const float* w4 = (const float*)d_in[8];
    const float* b4 = (const float*)d_in[9];
    const float* w5 = (const float*)d_in[10];
    const float* b5 = (const float*)d_in[11];
    const float* w6 = (const float*)d_in[12];
    const float* b6 = (const float*)d_in[13];
    const float* w7 = (const float*)d_in[14];
    const float* b7 = (const float*)d_in[15];

    const int B = 8, H = 352, W = 1216;
    const int H2 = 176, W2 = 608, H4 = 88, W4 = 304, H8 = 44, W8 = 152;
    const size_t F   = (size_t)64 * H * W;    // 27,394,048 f16 per 8-ch plane set
    const size_t H2s = (size_t)64 * H2 * W2;  // 6,848,512
    const size_t Qs  = (size_t)64 * H4 * W4;  // 1,712,128
    const size_t Es  = (size_t)64 * H8 * W8;  // 428,032

    const size_t needH = 4 * F * sizeof(f16) + 7168 * sizeof(float);
    if (ws_size < needH) return;

    f16* ws = (f16*)d_ws;
    f16* P0x = ws;            // full-res NHWC (xc, c), persists to final decoder
    f16* P0c = ws + F;
    f16* Ux  = ws + 2 * F;    // full-res ping
    f16* Uc  = ws + 3 * F;
    f16* D1x = ws + 2 * F;    // half-res set aliases region 2 (4*H2s == F)
    f16* D1c = D1x + H2s;
    f16* D2x = D1c + H2s;
    f16* D2c = D2x + H2s;
    f16* Q1x = ws + 3 * F;    // quarter + eighth alias region 3 (8.56M of F)
    f16* Q1c = Q1x + Qs;
    f16* Q2x = Q1c + Qs;
    f16* Q2c = Q2x + Qs;
    f16* E1x = Q2c + Qs;
    f16* E1c = E1x + Es;
    f16* E2x = E1c + Es;
    f16* E2c = E2x + Es;
    // decoder B-frags in region-3 slack (written after Uc dies)
    f16* DF4 = ws + 3 * F + 16777216;
    f16* DF5 = DF4 + 3072;
    f16* DF6 = DF5 + 3072;

    char* tail = (char*)d_ws + 4 * F * sizeof(f16);
    float* WT = (float*)tail;
    f16* BF2 = (f16*)(tail + 2048);
    f16* BF3 = (f16*)(tail + 9216);

    const float* s1 = WT + 200;
    const float* s2 = WT + 208;
    const float* s3 = WT + 216;
    const float* s4 = WT + 224;
    const float* s5 = WT + 232;
    const float* s6 = WT + 240;
    const float* s7 = WT + 248;
    const float* wp7 = WT + 256;

    prep_scalars<<<7, 256, 0, stream>>>(w1, w2, w3, w4, w5, w6, w7, WT);
    pack_enc_frag<<<2, 256, 0, stream>>>(w2, w3, BF2, BF3);

    auto nb = [](size_t n) { return (int)((n + 255) / 256); };
    auto tg = [](int nt) { int g = (nt + 3) / 4; return g < 2048 ? g : 2048; };

    const int ntF = B * H * ((W + 15) / 16);     // 214,016
    const int ntH = B * H2 * ((W2 + 15) / 16);   // 53,504
    const int ntQ = B * H4 * ((W4 + 15) / 16);   // 13,376
    const int ntE = B * H8 * ((W8 + 15) / 16);   // 3,520

    // Encoder
    nconv_l1<<<nb((size_t)B * H * (W / 4)), 256, 0, stream>>>(
        x0, c0, WT, s1, b1, P0x, P0c, B, H, W);
    enc5_mfma<<<tg(ntF), 256, 0, stream>>>(P0x, P0c, BF2, s2, b2, Ux, Uc, B, H, W);
    enc5_mfma<<<tg(ntF), 256, 0, stream>>>(Ux, Uc, BF3, s3, b3, P0x, P0c, B, H, W);
    pack_dec_frag<<<3, 256, 0, stream>>>(w4, w5, w6, DF4, DF5, DF6);  // Uc dead now
    pool_nhwc<<<nb((size_t)B * H2 * W2), 256, 0, stream>>>(P0x, P0c, D1x, D1c, B, H, W);
    enc5_mfma<<<tg(ntH), 256, 0, stream>>>(D1x, D1c, BF2, s2, b2, D2x, D2c, B, H2, W2);
    enc5_mfma<<<tg(ntH), 256, 0, stream>>>(D2x, D2c, BF3, s3, b3, D1x, D1c, B, H2, W2);
    pool_nhwc<<<nb((size_t)B * H4 * W4), 256, 0, stream>>>(D1x, D1c, Q1x, Q1c, B, H2, W2);
    enc5_mfma<<<tg(ntQ), 256, 0, stream>>>(Q1x, Q1c, BF2, s2, b2, Q2x, Q2c, B, H4, W4);
    pool_nhwc<<<nb((size_t)B * H8 * W8), 256, 0, stream>>>(Q2x, Q2c, E1x, E1c, B, H4, W4);
    enc5_mfma<<<tg(ntE), 256, 0, stream>>>(E1x, E1c, BF2, s2, b2, E2x, E2c, B, H8, W8);

    // Decoder
    dec3_mfma<0, 1, false><<<tg(ntQ), 256, 0, stream>>>(
        Q2x, Q2c, E2x, E2c, DF4, s4, b4, WT, WT, WT,
        Q1x, Q1c, (float*)nullptr, (float*)nullptr, B, H4, W4);
    dec3_mfma<0, 1, false><<<tg(ntH), 256, 0, stream>>>(
        D1x, D1c, Q1x, Q1c, DF5, s5, b5, WT, WT, WT,
        D2x, D2c, (float*)nullptr, (float*)nullptr, B, H2, W2);

    float* outx = (float*)d_out;
    float* outc = outx + (size_t)B * H * W;
    dec3_mfma<1, 0, true><<<tg(ntF), 256, 0, stream>>>(
        D2x, D2c, P0x, P0c, DF6, s6, b6, wp7, s7, b7,
        (f16*)nullptr, (f16*)nullptr, outx, outc, B, H, W);
}

// Round 5
// 605.996 us; speedup vs baseline: 4.4557x; 1.2214x over previous
//
#include <hip/hip_runtime.h>
#include <cmath>

#define EPSV 1e-20f

typedef _Float16 f16;
typedef _Float16 v8h __attribute__((ext_vector_type(8)));
typedef _Float16 h4 __attribute__((ext_vector_type(4)));
typedef float v4f __attribute__((ext_vector_type(4)));
typedef float f32x2 __attribute__((ext_vector_type(2)));

__device__ __forceinline__ float softplusf(float x) {
    return fmaxf(x, 0.f) + log1pf(expf(-fabsf(x)));
}

__device__ __forceinline__ v8h v8h_zero() {
    v8h z = {0, 0, 0, 0, 0, 0, 0, 0};
    return z;
}

// ---------------------------------------------------------------------------
// WT float layout (at byte offset 4F*2 in ws):
//   wp1 @ [0..199]  (softplus'd 5x5x1x8, OIHW)
//   s_l @ [200 + (l-1)*8]  l=1..7  (per-co kernel sums; s7 is 1 value @248)
//   wp7 @ [256..263]
// BF2 (f16, 7*64*8) @ byte +2048 ; BF3 @ byte +9216
// ---------------------------------------------------------------------------
__global__ void prep_scalars(const float* __restrict__ w1, const float* __restrict__ w2,
                             const float* __restrict__ w3, const float* __restrict__ w4,
                             const float* __restrict__ w5, const float* __restrict__ w6,
                             const float* __restrict__ w7, float* __restrict__ WT) {
    __shared__ float lds[1600];
    const float* srcs[7] = {w1, w2, w3, w4, w5, w6, w7};
    const int ns[7]    = {200, 1600, 1600, 1152, 1152, 1152, 8};
    const int pers[7]  = {25, 200, 200, 144, 144, 144, 8};
    const int couts[7] = {8, 8, 8, 8, 8, 8, 1};
    int t = blockIdx.x;
    const float* src = srcs[t];
    int n = ns[t];
    for (int i = threadIdx.x; i < n; i += blockDim.x) {
        float v = softplusf(src[i]);
        lds[i] = v;
        if (t == 0) WT[i] = v;        // wp1
        if (t == 6) WT[256 + i] = v;  // wp7
    }
    __syncthreads();
    if ((int)threadIdx.x < couts[t]) {
        float s = 0.f;
        int per = pers[t];
        for (int i = 0; i < per; ++i) s += lds[threadIdx.x * per + i];
        WT[200 + t * 8 + threadIdx.x] = s;
    }
}

// Weight fragment pack, encoder 5x5 8ci: lane l -> co=l&15, sub=l>>4; element
// j = ci; k-slot (g,sub) = tap g*4+sub. co>=8 and tap>24 are zero.
__global__ void pack_enc_frag(const float* __restrict__ w2, const float* __restrict__ w3,
                              f16* __restrict__ dst2, f16* __restrict__ dst3) {
    const float* w = blockIdx.x ? w3 : w2;
    f16* dst = blockIdx.x ? dst3 : dst2;
    for (int i = threadIdx.x; i < 7 * 64 * 8; i += blockDim.x) {
        int g = i >> 9;
        int l = (i >> 3) & 63;
        int j = i & 7;
        int co = l & 15, sub = l >> 4;
        int t = g * 4 + sub;
        float v = 0.f;
        if (co < 8 && t <= 24) {
            v = softplusf(w[((co * 8 + j) * 5 + t / 5) * 5 + t % 5]);
        }
        dst[i] = (f16)v;
    }
}

// Weight fragment pack, decoder 3x3 16ci: groups 0-2 = src0(ci 0-7), 3-5 = src1.
__global__ void pack_dec_frag(const float* __restrict__ w4, const float* __restrict__ w5,
                              const float* __restrict__ w6,
                              f16* __restrict__ dst4, f16* __restrict__ dst5,
                              f16* __restrict__ dst6) {
    const float* ww[3] = {w4, w5, w6};
    f16* dd[3] = {dst4, dst5, dst6};
    const float* w = ww[blockIdx.x];
    f16* dst = dd[blockIdx.x];
    for (int i = threadIdx.x; i < 6 * 64 * 8; i += blockDim.x) {
        int g = i >> 9;
        int l = (i >> 3) & 63;
        int j = i & 7;
        int co = l & 15, sub = l >> 4;
        int srcsel = g / 3, gs = g % 3;
        int t = gs * 4 + sub;
        float v = 0.f;
        if (co < 8 && t <= 8) {
            int ci = srcsel * 8 + j;
            v = softplusf(w[((co * 16 + ci) * 3 + t / 3) * 3 + t % 3]);
        }
        dst[i] = (f16)v;
    }
}

// ---------------------------------------------------------------------------
__device__ __forceinline__ void load_row8_f(const float* __restrict__ row, int c0, int W,
                                            float v[8]) {
    if (c0 >= 0 && c0 + 8 <= W) {
#pragma unroll
        for (int i = 0; i < 4; ++i) {
            f32x2 t = *(const f32x2*)(row + c0 + 2 * i);
            v[2 * i] = t[0];
            v[2 * i + 1] = t[1];
        }
    } else {
#pragma unroll
        for (int i = 0; i < 8; ++i) {
            int c = c0 + i;
            v[i] = (c >= 0 && c < W) ? row[c] : 0.f;
        }
    }
}

// ---------------------------------------------------------------------------
// Layer 1 (CIN=1) VALU: fp32 planar (x,c) -> f16 NHWC (xc, c). 5x5 pad 2, PX=4.
// ---------------------------------------------------------------------------
__global__ void __launch_bounds__(256) nconv_l1(
    const float* __restrict__ x0, const float* __restrict__ c0,
    const float* __restrict__ wp, const float* __restrict__ ssum,
    const float* __restrict__ bias,
    f16* __restrict__ xcout, f16* __restrict__ cout,
    int B, int H, int W) {
    __shared__ __attribute__((aligned(16))) float wl[200];  // [kh][kw][co]
    for (int i = threadIdx.x; i < 200; i += 256) {
        int co = i & 7, r = i >> 3;
        wl[i] = wp[co * 25 + r];
    }
    __syncthreads();

    const int Wq = W >> 2;
    int idx = blockIdx.x * 256 + threadIdx.x;
    int total = B * H * Wq;
    if (idx >= total) return;
    int w0 = (idx % Wq) << 2;
    int h = (idx / Wq) % H;
    int b = idx / (Wq * H);
    const int HW = H * W;

    float den[4][8] = {}, nom[4][8] = {};
    const float* cp = c0 + (size_t)b * HW;
    const float* xp = x0 + (size_t)b * HW;

    for (int kh = 0; kh < 5; ++kh) {
        int ih = h + kh - 2;
        if (ih < 0 || ih >= H) continue;
        float cv[8], xr[8], xv[8];
        load_row8_f(cp + (size_t)ih * W, w0 - 2, W, cv);
        load_row8_f(xp + (size_t)ih * W, w0 - 2, W, xr);
#pragma unroll
        for (int i = 0; i < 8; ++i) xv[i] = xr[i] * cv[i];
        const float* wrow = &wl[kh * 5 * 8];
#pragma unroll
        for (int kw = 0; kw < 5; ++kw) {
            const float4* wq = (const float4*)&wrow[kw * 8];
            float4 wa = wq[0], wb = wq[1];
            float wv[8] = {wa.x, wa.y, wa.z, wa.w, wb.x, wb.y, wb.z, wb.w};
#pragma unroll
            for (int co = 0; co < 8; ++co)
#pragma unroll
                for (int p = 0; p < 4; ++p) {
                    den[p][co] = fmaf(wv[co], cv[p + kw], den[p][co]);
                    nom[p][co] = fmaf(wv[co], xv[p + kw], nom[p][co]);
                }
        }
    }

    float rssv[8], bbv[8];
#pragma unroll
    for (int co = 0; co < 8; ++co) {
        rssv[co] = __builtin_amdgcn_rcpf(ssum[co]);
        bbv[co] = bias[co];
    }
    unsigned pa = (unsigned)(((b * H + h) * W + w0) * 8);
#pragma unroll
    for (int p = 0; p < 4; ++p) {
        v8h xc8, c8;
#pragma unroll
        for (int co = 0; co < 8; ++co) {
            float d = den[p][co];
            float cc = d * rssv[co];
            float xo = nom[p][co] * __builtin_amdgcn_rcpf(d + EPSV) + bbv[co];
            xc8[co] = (f16)(xo * cc);
            c8[co] = (f16)cc;
        }
        *(v8h*)(xcout + pa + p * 8) = xc8;
        *(v8h*)(cout + pa + p * 8) = c8;
    }
}

// ---------------------------------------------------------------------------
// Pool-gather NHWC, 2 output pixels per thread (coalesced 64B row reads).
// 2x2 argmax of c per channel (first occurrence (0,0),(0,1),(1,0),(1,1)).
// ---------------------------------------------------------------------------
__global__ void __launch_bounds__(256) pool_nhwc(
    const f16* __restrict__ xc, const f16* __restrict__ c,
    f16* __restrict__ xo, f16* __restrict__ co_,
    int B, int H, int W) {
    int H2 = H >> 1, W2 = W >> 1, Wh = W2 >> 1;
    int idx = blockIdx.x * 256 + threadIdx.x;
    int total = B * H2 * Wh;
    if (idx >= total) return;
    int wo = (idx % Wh) * 2;
    int ho = (idx / Wh) % H2;
    int b = idx / (Wh * H2);
    unsigned base = (unsigned)(((b * H + 2 * ho) * W + 2 * wo) * 8);
    unsigned rb = (unsigned)(W * 8);
    v8h c0r[4], c1r[4], x0r[4], x1r[4];
#pragma unroll
    for (int i = 0; i < 4; ++i) {
        c0r[i] = *(const v8h*)(c + base + 8 * i);
        c1r[i] = *(const v8h*)(c + base + rb + 8 * i);
        x0r[i] = *(const v8h*)(xc + base + 8 * i);
        x1r[i] = *(const v8h*)(xc + base + rb + 8 * i);
    }
    unsigned oa = (unsigned)(((b * H2 + ho) * W2 + wo) * 8);
#pragma unroll
    for (int p = 0; p < 2; ++p) {
        v8h xr, cr;
#pragma unroll
        for (int e = 0; e < 8; ++e) {
            float b0 = (float)c0r[2 * p][e], b1 = (float)c0r[2 * p + 1][e];
            float b2 = (float)c1r[2 * p][e], b3 = (float)c1r[2 * p + 1][e];
            float cb = b0;
            float xv = (float)x0r[2 * p][e];
            if (b1 > cb) { cb = b1; xv = (float)x0r[2 * p + 1][e]; }
            if (b2 > cb) { cb = b2; xv = (float)x1r[2 * p][e]; }
            if (b3 > cb) { cb = b3; xv = (float)x1r[2 * p + 1][e]; }
            xr[e] = (f16)(xv * 0.25f);
            cr[e] = (f16)(cb * 0.25f);
        }
        *(v8h*)(xo + oa + p * 8) = xr;
        *(v8h*)(co_ + oa + p * 8) = cr;
    }
}

// ---------------------------------------------------------------------------
// Encoder nconv via MFMA, column sweep. mfma(weights, pixels, acc):
// D col (lane&15) = pixel, D row (sub*4+reg) = co. One wave per 16-wide tile
// column, walking CH rows. 5x5 pad 2, 8ci -> 8co.
// ---------------------------------------------------------------------------
__global__ void __launch_bounds__(256) enc5_mfma(
    const f16* __restrict__ xcin, const f16* __restrict__ cin,
    const f16* __restrict__ bfrag, const float* __restrict__ ssum,
    const float* __restrict__ bias,
    f16* __restrict__ xcout, f16* __restrict__ cout,
    int B, int H, int W, int CH) {
    const int lane = threadIdx.x & 63;
    const int wid = threadIdx.x >> 6;
    const int m = lane & 15, sub = lane >> 4;
    const int tilesW = (W + 15) >> 4;
    const int tw = blockIdx.x * 4 + wid;
    if (tw >= tilesW) return;
    const int w0 = tw << 4;
    const int b = blockIdx.z;
    const int h0 = blockIdx.y * CH;
    const int hend = min(h0 + CH, H);

    v8h bf[7];
#pragma unroll
    for (int g = 0; g < 7; ++g)
        bf[g] = *(const v8h*)(bfrag + ((g << 6) + lane) * 8);

    int dh[7], offg[7], wq8[7];
    bool okw[7];
#pragma unroll
    for (int g = 0; g < 7; ++g) {
        int t = g * 4 + sub;
        if (t > 24) t = 24;  // pad slots: address aliases a real tap, weight = 0
        dh[g] = t / 5 - 2;
        int dwv = t % 5 - 2;
        offg[g] = (dh[g] * W + dwv) * 8;
        int wwp = w0 + m + dwv;
        okw[g] = (wwp >= 0) && (wwp < W);
        wq8[g] = min(max(wwp, 0), W - 1) * 8;
    }
    const bool wInt = (w0 >= 2) && (w0 + 17 < W);

    float4 ssv = {1.f, 1.f, 1.f, 1.f}, bbv = {0.f, 0.f, 0.f, 0.f};
    if (sub < 2) {
        ssv = *(const float4*)(ssum + sub * 4);
        bbv = *(const float4*)(bias + sub * 4);
    }
    float rssv[4];
#pragma unroll
    for (int j = 0; j < 4; ++j) rssv[j] = __builtin_amdgcn_rcpf(((const float*)&ssv)[j]);

    const int W8 = W * 8;
    const unsigned bb8 = (unsigned)(b * H) * (unsigned)W8;
    unsigned pbase = bb8 + (unsigned)h0 * W8 + (unsigned)(w0 + m) * 8;
    unsigned sbase = bb8 + (unsigned)h0 * W8 + (unsigned)(w0 + m) * 8 + sub * 4;
    const bool doStore = (sub < 2) && (w0 + m < W);

    for (int h = h0; h < hend; ++h) {
        v4f accd = {0.f, 0.f, 0.f, 0.f}, accn = {0.f, 0.f, 0.f, 0.f};
        if (wInt && h >= 2 && h < H - 2) {
#pragma unroll
            for (int g = 0; g < 7; ++g) {
                unsigned a = pbase + offg[g];
                v8h pc = *(const v8h*)(cin + a);
                v8h px = *(const v8h*)(xcin + a);
                accd = __builtin_amdgcn_mfma_f32_16x16x32_f16(bf[g], pc, accd, 0, 0, 0);
                accn = __builtin_amdgcn_mfma_f32_16x16x32_f16(bf[g], px, accn, 0, 0, 0);
            }
        } else {
#pragma unroll
            for (int g = 0; g < 7; ++g) {
                int hh = h + dh[g];
                bool ok = okw[g] && (hh >= 0) && (hh < H);
                int hc = min(max(hh, 0), H - 1);
                unsigned a = bb8 + (unsigned)hc * W8 + wq8[g];
                v8h pc = *(const v8h*)(cin + a);
                v8h px = *(const v8h*)(xcin + a);
                if (!ok) { pc = v8h_zero(); px = v8h_zero(); }
                accd = __builtin_amdgcn_mfma_f32_16x16x32_f16(bf[g], pc, accd, 0, 0, 0);
                accn = __builtin_amdgcn_mfma_f32_16x16x32_f16(bf[g], px, accn, 0, 0, 0);
            }
        }
        if (doStore) {
            h4 xo8, c8;
#pragma unroll
            for (int j = 0; j < 4; ++j) {
                float d = accd[j];
                float cc = d * rssv[j];
                float x = accn[j] * __builtin_amdgcn_rcpf(d + EPSV) + ((const float*)&bbv)[j];
                c8[j] = (f16)cc;
                xo8[j] = (f16)(x * cc);
            }
            *(h4*)(cout + sbase) = c8;
            *(h4*)(xcout + sbase) = xo8;
        }
        pbase += W8;
        sbase += W8;
    }
}

// ---------------------------------------------------------------------------
// Decoder nconv via MFMA, column sweep: concat(src0, src1) 16ch -> 8ch, 3x3
// pad 1, src sampled at (>>SH). FUSE7: fused final 1x1, fp32 1-ch outputs.
// ---------------------------------------------------------------------------
template <int SH0, int SH1, bool FUSE7>
__global__ void __launch_bounds__(256) dec3_mfma(
    const f16* __restrict__ xc0, const f16* __restrict__ c0p,
    const f16* __restrict__ xc1, const f16* __restrict__ c1p,
    const f16* __restrict__ bfrag,
    const float* __restrict__ ssum, const float* __restrict__ bias,
    const float* __restrict__ wp7, const float* __restrict__ s7p,
    const float* __restrict__ b7p,
    f16* __restrict__ xcout, f16* __restrict__ ccout,
    float* __restrict__ xoutf, float* __restrict__ coutf,
    int B, int H, int W, int CH) {
    const int lane = threadIdx.x & 63;
    const int wid = threadIdx.x >> 6;
    const int m = lane & 15, sub = lane >> 4;
    const int tilesW = W >> 4;
    const int tw = blockIdx.x * 4 + wid;
    if (tw >= tilesW) return;
    const int w0 = tw << 4;
    const int b = blockIdx.z;
    const int h0 = blockIdx.y * CH;
    const int hend = min(h0 + CH, H);

    v8h bf[6];
#pragma unroll
    for (int g = 0; g < 6; ++g)
        bf[g] = *(const v8h*)(bfrag + ((g << 6) + lane) * 8);

    int dhv[3], dwv[3];
#pragma unroll
    for (int gs = 0; gs < 3; ++gs) {
        int t = gs * 4 + sub;
        if (t > 8) t = 8;
        dhv[gs] = t / 3 - 1;
        dwv[gs] = t % 3 - 1;
    }
    // Per-source precompute: clamped w offsets (f16 units) and validity.
    const int Hs0 = H >> SH0, Ws0 = W >> SH0;
    const int Hs1 = H >> SH1, Ws1 = W >> SH1;
    int wq0[3], wq1[3];
    bool okw[3];
#pragma unroll
    for (int gs = 0; gs < 3; ++gs) {
        int wwp = w0 + m + dwv[gs];
        okw[gs] = (wwp >= 0) && (wwp < W);
        int wc = min(max(wwp, 0), W - 1);
        wq0[gs] = (wc >> SH0) * 8;
        wq1[gs] = (wc >> SH1) * 8;
    }
    const int Wr0 = Ws0 * 8, Wr1 = Ws1 * 8;
    const unsigned bs0 = (unsigned)(b * Hs0) * (unsigned)Wr0;
    const unsigned bs1 = (unsigned)(b * Hs1) * (unsigned)Wr1;

    float4 ssv = {1.f, 1.f, 1.f, 1.f}, bbv = {0.f, 0.f, 0.f, 0.f};
    float4 w7v = {0.f, 0.f, 0.f, 0.f};
    if (sub < 2) {
        ssv = *(const float4*)(ssum + sub * 4);
        bbv = *(const float4*)(bias + sub * 4);
        if (FUSE7) w7v = *(const float4*)(wp7 + sub * 4);
    }
    float rssv[4];
#pragma unroll
    for (int j = 0; j < 4; ++j) rssv[j] = __builtin_amdgcn_rcpf(((const float*)&ssv)[j]);
    float rs7 = 0.f, b7v = 0.f;
    if (FUSE7) { rs7 = __builtin_amdgcn_rcpf(s7p[0]); b7v = b7p[0]; }

    const int W8 = W * 8;
    const unsigned obb = (unsigned)(b * H) * (unsigned)W8;
    unsigned sbase = obb + (unsigned)h0 * W8 + (unsigned)(w0 + m) * 8 + sub * 4;
    unsigned opix = (unsigned)(b * H + h0) * (unsigned)W + (unsigned)w0;
    const bool doStore = (sub < 2);

    for (int h = h0; h < hend; ++h) {
        v4f accd = {0.f, 0.f, 0.f, 0.f}, accn = {0.f, 0.f, 0.f, 0.f};
#pragma unroll
        for (int gs = 0; gs < 3; ++gs) {
            int hh = h + dhv[gs];
            bool ok = okw[gs] && (hh >= 0) && (hh < H);
            int hc = min(max(hh, 0), H - 1);
            unsigned a = bs0 + (unsigned)(hc >> SH0) * Wr0 + wq0[gs];
            v8h pc = *(const v8h*)(c0p + a);
            v8h px = *(const v8h*)(xc0 + a);
            if (!ok) { pc = v8h_zero(); px = v8h_zero(); }
            accd = __builtin_amdgcn_mfma_f32_16x16x32_f16(bf[gs], pc, accd, 0, 0, 0);
            accn = __builtin_amdgcn_mfma_f32_16x16x32_f16(bf[gs], px, accn, 0, 0, 0);
        }
#pragma unroll
        for (int gs = 0; gs < 3; ++gs) {
            int hh = h + dhv[gs];
            bool ok = okw[gs] && (hh >= 0) && (hh < H);
            int hc = min(max(hh, 0), H - 1);
            unsigned a = bs1 + (unsigned)(hc >> SH1) * Wr1 + wq1[gs];
            v8h pc = *(const v8h*)(c1p + a);
            v8h px = *(const v8h*)(xc1 + a);
            if (!ok) { pc = v8h_zero(); px = v8h_zero(); }
            accd = __builtin_amdgcn_mfma_f32_16x16x32_f16(bf[3 + gs], pc, accd, 0, 0, 0);
            accn = __builtin_amdgcn_mfma_f32_16x16x32_f16(bf[3 + gs], px, accn, 0, 0, 0);
        }

        if (FUSE7) {
            float td = 0.f, tn = 0.f;
#pragma unroll
            for (int j = 0; j < 4; ++j) {
                float d = accd[j];  // exactly 0 for co>=8 (weight rows zeroed)
                float cc = d * rssv[j];
                float o = accn[j] * __builtin_amdgcn_rcpf(d + EPSV) + ((const float*)&bbv)[j];
                td = fmaf(((const float*)&w7v)[j], cc, td);
                tn = fmaf(((const float*)&w7v)[j], o * cc, tn);
            }
            td += __shfl_xor(td, 16);
            tn += __shfl_xor(tn, 16);
            td += __shfl_xor(td, 32);
            tn += __shfl_xor(tn, 32);
            if (sub == 0) {
                xoutf[opix + m] = tn * __builtin_amdgcn_rcpf(td + EPSV) + b7v;
            } else if (sub == 1) {
                coutf[opix + m] = td * rs7;
            }
            opix += W;
        } else if (doStore) {
            h4 xo8, c8;
#pragma unroll
            for (int j = 0; j < 4; ++j) {
                float d = accd[j];
                float cc = d * rssv[j];
                float x = accn[j] * __builtin_amdgcn_rcpf(d + EPSV) + ((const float*)&bbv)[j];
                c8[j] = (f16)cc;
                xo8[j] = (f16)(x * cc);
            }
            *(h4*)(ccout + sbase) = c8;
            *(h4*)(xcout + sbase) = xo8;
        }
        sbase += W8;
    }
}

// ---------------------------------------------------------------------------
extern "C" void kernel_launch(void* const* d_in, const int* in_sizes, int n_in,
                              void* d_out, int out_size, void* d_ws, size_t ws_size,
                              hipStream_t stream) {
    const float* x0 = (const float*)d_in[0];
    const float* c0 = (const float*)d_in[1];
    const float* w1 = (const float*)d_in[2];
    const float* b1 = (const float*)d_in[3];
    const float* w2 = (const float*)d_in[4];
    const float* b2 = (const float*)d_in[5];
    const float* w3 = (const float*)d_in[6];
    const float* b3 = (const float*)d_in[7];
    const float* w4 = (const float*)d_in[8];
    const float* b4 = (const float*)d_in[9];
    const float* w5 = (const float*)d_in[10];
    const float* b5 = (const float*)d_in[11];
    const float* w6 = (const float*)d_in[12];
    const float* b6 = (const float*)d_in[13];
    const float* w7 = (const float*)d_in[14];
    const float* b7 = (const float*)d_in[15];

    const int B = 8, H = 352, W = 1216;
    const int H2 = 176, W2 = 608, H4 = 88, W4 = 304, H8 = 44, W8 = 152;
    const size_t F   = (size_t)64 * H * W;
    const size_t H2s = (size_t)64 * H2 * W2;
    const size_t Qs  = (size_t)64 * H4 * W4;
    const size_t Es  = (size_t)64 * H8 * W8;

    const size_t needH = 4 * F * sizeof(f16) + 7168 * sizeof(float);
    if (ws_size < needH) return;

    f16* ws = (f16*)d_ws;
    f16* P0x = ws;            // full-res NHWC (xc, c), persists to final decoder
    f16* P0c = ws + F;
    f16* Ux  = ws + 2 * F;    // full-res ping
    f16* Uc  = ws + 3 * F;
    f16* D1x = ws + 2 * F;    // half-res set aliases region 2
    f16* D1c = D1x + H2s;
    f16* D2x = D1c + H2s;
    f16* D2c = D2x + H2s;
    f16* Q1x = ws + 3 * F;    // quarter + eighth alias region 3
    f16* Q1c = Q1x + Qs;
    f16* Q2x = Q1c + Qs;
    f16* Q2c = Q2x + Qs;
    f16* E1x = Q2c + Qs;
    f16* E1c = E1x + Es;
    f16* E2x = E1c + Es;
    f16* E2c = E2x + Es;
    f16* DF4 = ws + 3 * F + 16777216;  // decoder frags in region-3 slack
    f16* DF5 = DF4 + 3072;
    f16* DF6 = DF5 + 3072;

    char* tail = (char*)d_ws + 4 * F * sizeof(f16);
    float* WT = (float*)tail;
    f16* BF2 = (f16*)(tail + 2048);
    f16* BF3 = (f16*)(tail + 9216);

    const float* s1 = WT + 200;
    const float* s2 = WT + 208;
    const float* s3 = WT + 216;
    const float* s4 = WT + 224;
    const float* s5 = WT + 232;
    const float* s6 = WT + 240;
    const float* s7 = WT + 248;
    const float* wp7 = WT + 256;

    prep_scalars<<<7, 256, 0, stream>>>(w1, w2, w3, w4, w5, w6, w7, WT);
    pack_enc_frag<<<2, 256, 0, stream>>>(w2, w3, BF2, BF3);

    auto nb = [](size_t n) { return (int)((n + 255) / 256); };
    // Column-sweep grids: x = ceil(tilesW/4), y = h-chunks, z = B.
    const dim3 gF(19, 16, 8);   // tilesW=76,  CH=22
    const dim3 gH(10, 16, 8);   // tilesW=38,  CH=11
    const dim3 gQ(5, 11, 8);    // tilesW=19,  CH=8
    const dim3 gE(3, 11, 8);    // tilesW=10,  CH=4

    // Encoder
    nconv_l1<<<nb((size_t)B * H * (W / 4)), 256, 0, stream>>>(
        x0, c0, WT, s1, b1, P0x, P0c, B, H, W);
    enc5_mfma<<<gF, 256, 0, stream>>>(P0x, P0c, BF2, s2, b2, Ux, Uc, B, H, W, 22);
    enc5_mfma<<<gF, 256, 0, stream>>>(Ux, Uc, BF3, s3, b3, P0x, P0c, B, H, W, 22);
    pack_dec_frag<<<3, 256, 0, stream>>>(w4, w5, w6, DF4, DF5, DF6);  // Uc dead now
    pool_nhwc<<<nb((size_t)B * H2 * (W2 / 2)), 256, 0, stream>>>(P0x, P0c, D1x, D1c, B, H, W);
    enc5_mfma<<<gH, 256, 0, stream>>>(D1x, D1c, BF2, s2, b2, D2x, D2c, B, H2, W2, 11);
    enc5_mfma<<<gH, 256, 0, stream>>>(D2x, D2c, BF3, s3, b3, D1x, D1c, B, H2, W2, 11);
    pool_nhwc<<<nb((size_t)B * H4 * (W4 / 2)), 256, 0, stream>>>(D1x, D1c, Q1x, Q1c, B, H2, W2);
    enc5_mfma<<<gQ, 256, 0, stream>>>(Q1x, Q1c, BF2, s2, b2, Q2x, Q2c, B, H4, W4, 8);
    pool_nhwc<<<nb((size_t)B * H8 * (W8 / 2)), 256, 0, stream>>>(Q2x, Q2c, E1x, E1c, B, H4, W4);
    enc5_mfma<<<gE, 256, 0, stream>>>(E1x, E1c, BF2, s2, b2, E2x, E2c, B, H8, W8, 4);

    // Decoder
    dec3_mfma<0, 1, false><<<gQ, 256, 0, stream>>>(
        Q2x, Q2c, E2x, E2c, DF4, s4, b4, WT, WT, WT,
        Q1x, Q1c, (float*)nullptr, (float*)nullptr, B, H4, W4, 8);
    dec3_mfma<0, 1, false><<<gH, 256, 0, stream>>>(
        D1x, D1c, Q1x, Q1c, DF5, s5, b5, WT, WT, WT,
        D2x, D2c, (float*)nullptr, (float*)nullptr, B, H2, W2, 11);

    float* outx = (float*)d_out;
    float* outc = outx + (size_t)B * H * W;
    dec3_mfma<1, 0, true><<<gF, 256, 0, stream>>>(
        D2x, D2c, P0x, P0c, DF6, s6, b6, wp7, s7, b7,
        (f16*)nullptr, (f16*)nullptr, outx, outc, B, H, W, 22);
}

// Round 6
// 420.955 us; speedup vs baseline: 6.4142x; 1.4396x over previous
//
#include <hip/hip_runtime.h>
#include <cmath>

#define EPSV 1e-20f

typedef _Float16 f16;
typedef _Float16 v8h __attribute__((ext_vector_type(8)));
typedef _Float16 h4 __attribute__((ext_vector_type(4)));
typedef float v4f __attribute__((ext_vector_type(4)));
typedef float f32x2 __attribute__((ext_vector_type(2)));

__device__ __forceinline__ float softplusf(float x) {
    return fmaxf(x, 0.f) + log1pf(expf(-fabsf(x)));
}

__device__ __forceinline__ v8h v8h_zero() {
    v8h z = {0, 0, 0, 0, 0, 0, 0, 0};
    return z;
}

// ---------------------------------------------------------------------------
// WT float layout (at byte offset 4F*2 in ws):
//   wp1 @ [0..199]  s_l @ [200 + (l-1)*8]  wp7 @ [256..263]
// BF2 (f16, 7*64*8) @ byte +2048 ; BF3 @ byte +9216
// ---------------------------------------------------------------------------
__global__ void prep_scalars(const float* __restrict__ w1, const float* __restrict__ w2,
                             const float* __restrict__ w3, const float* __restrict__ w4,
                             const float* __restrict__ w5, const float* __restrict__ w6,
                             const float* __restrict__ w7, float* __restrict__ WT) {
    __shared__ float lds[1600];
    const float* srcs[7] = {w1, w2, w3, w4, w5, w6, w7};
    const int ns[7]    = {200, 1600, 1600, 1152, 1152, 1152, 8};
    const int pers[7]  = {25, 200, 200, 144, 144, 144, 8};
    const int couts[7] = {8, 8, 8, 8, 8, 8, 1};
    int t = blockIdx.x;
    const float* src = srcs[t];
    int n = ns[t];
    for (int i = threadIdx.x; i < n; i += blockDim.x) {
        float v = softplusf(src[i]);
        lds[i] = v;
        if (t == 0) WT[i] = v;        // wp1
        if (t == 6) WT[256 + i] = v;  // wp7
    }
    __syncthreads();
    if ((int)threadIdx.x < couts[t]) {
        float s = 0.f;
        int per = pers[t];
        for (int i = 0; i < per; ++i) s += lds[threadIdx.x * per + i];
        WT[200 + t * 8 + threadIdx.x] = s;
    }
}

// Encoder 5x5 8ci weight frags, rotation packing:
//  g<5 : (kh=g,   kw=sub)          — rotating groups, dh=g-2, dw=sub-2
//  g==5: (kh=sub, kw=4)            — dw=+2 column, dh=sub-2
//  g==6: (kh=4,   kw=4) sub==0 only
__global__ void pack_enc_frag(const float* __restrict__ w2, const float* __restrict__ w3,
                              f16* __restrict__ dst2, f16* __restrict__ dst3) {
    const float* w = blockIdx.x ? w3 : w2;
    f16* dst = blockIdx.x ? dst3 : dst2;
    for (int i = threadIdx.x; i < 7 * 64 * 8; i += blockDim.x) {
        int g = i >> 9;
        int l = (i >> 3) & 63;
        int j = i & 7;
        int co = l & 15, sub = l >> 4;
        float v = 0.f;
        if (co < 8) {
            int kh = 0, kw = 0;
            bool valid = true;
            if (g < 5) { kh = g; kw = sub; }
            else if (g == 5) { kh = sub; kw = 4; }
            else { kh = 4; kw = 4; valid = (sub == 0); }
            if (valid) v = softplusf(w[((co * 8 + j) * 5 + kh) * 5 + kw]);
        }
        dst[i] = (f16)v;
    }
}

// Decoder 3x3 16ci weight frags: g = block*3 + kh (block 0 = ci 0-7, 1 = ci 8-15),
// kw = sub (sub 3 zero), element j = ci within block.
__global__ void pack_dec_frag(const float* __restrict__ w4, const float* __restrict__ w5,
                              const float* __restrict__ w6,
                              f16* __restrict__ dst4, f16* __restrict__ dst5,
                              f16* __restrict__ dst6) {
    const float* ww[3] = {w4, w5, w6};
    f16* dd[3] = {dst4, dst5, dst6};
    const float* w = ww[blockIdx.x];
    f16* dst = dd[blockIdx.x];
    for (int i = threadIdx.x; i < 6 * 64 * 8; i += blockDim.x) {
        int g = i >> 9;
        int l = (i >> 3) & 63;
        int j = i & 7;
        int co = l & 15, sub = l >> 4;
        int block = g / 3, kh = g % 3;
        float v = 0.f;
        if (co < 8 && sub < 3) {
            v = softplusf(w[((co * 16 + block * 8 + j) * 3 + kh) * 3 + sub]);
        }
        dst[i] = (f16)v;
    }
}

// ---------------------------------------------------------------------------
__device__ __forceinline__ void load_row8_f(const float* __restrict__ row, int c0, int W,
                                            float v[8]) {
    if (c0 >= 0 && c0 + 8 <= W) {
#pragma unroll
        for (int i = 0; i < 4; ++i) {
            f32x2 t = *(const f32x2*)(row + c0 + 2 * i);
            v[2 * i] = t[0];
            v[2 * i + 1] = t[1];
        }
    } else {
#pragma unroll
        for (int i = 0; i < 8; ++i) {
            int c = c0 + i;
            v[i] = (c >= 0 && c < W) ? row[c] : 0.f;
        }
    }
}

// ---------------------------------------------------------------------------
// Layer 1 (CIN=1) VALU: fp32 planar (x,c) -> f16 NHWC (xc, c). 5x5 pad 2, PX=4.
// ---------------------------------------------------------------------------
__global__ void __launch_bounds__(256) nconv_l1(
    const float* __restrict__ x0, const float* __restrict__ c0,
    const float* __restrict__ wp, const float* __restrict__ ssum,
    const float* __restrict__ bias,
    f16* __restrict__ xcout, f16* __restrict__ cout,
    int B, int H, int W) {
    __shared__ __attribute__((aligned(16))) float wl[200];  // [kh][kw][co]
    for (int i = threadIdx.x; i < 200; i += 256) {
        int co = i & 7, r = i >> 3;
        wl[i] = wp[co * 25 + r];
    }
    __syncthreads();

    const int Wq = W >> 2;
    int idx = blockIdx.x * 256 + threadIdx.x;
    int total = B * H * Wq;
    if (idx >= total) return;
    int w0 = (idx % Wq) << 2;
    int h = (idx / Wq) % H;
    int b = idx / (Wq * H);
    const int HW = H * W;

    float den[4][8] = {}, nom[4][8] = {};
    const float* cp = c0 + (size_t)b * HW;
    const float* xp = x0 + (size_t)b * HW;

    for (int kh = 0; kh < 5; ++kh) {
        int ih = h + kh - 2;
        if (ih < 0 || ih >= H) continue;
        float cv[8], xr[8], xv[8];
        load_row8_f(cp + (size_t)ih * W, w0 - 2, W, cv);
        load_row8_f(xp + (size_t)ih * W, w0 - 2, W, xr);
#pragma unroll
        for (int i = 0; i < 8; ++i) xv[i] = xr[i] * cv[i];
        const float* wrow = &wl[kh * 5 * 8];
#pragma unroll
        for (int kw = 0; kw < 5; ++kw) {
            const float4* wq = (const float4*)&wrow[kw * 8];
            float4 wa = wq[0], wb = wq[1];
            float wv[8] = {wa.x, wa.y, wa.z, wa.w, wb.x, wb.y, wb.z, wb.w};
#pragma unroll
            for (int co = 0; co < 8; ++co)
#pragma unroll
                for (int p = 0; p < 4; ++p) {
                    den[p][co] = fmaf(wv[co], cv[p + kw], den[p][co]);
                    nom[p][co] = fmaf(wv[co], xv[p + kw], nom[p][co]);
                }
        }
    }

    float rssv[8], bbv[8];
#pragma unroll
    for (int co = 0; co < 8; ++co) {
        rssv[co] = __builtin_amdgcn_rcpf(ssum[co]);
        bbv[co] = bias[co];
    }
    unsigned pa = (unsigned)(((b * H + h) * W + w0) * 8);
#pragma unroll
    for (int p = 0; p < 4; ++p) {
        v8h xc8, c8;
#pragma unroll
        for (int co = 0; co < 8; ++co) {
            float d = den[p][co];
            float cc = d * rssv[co];
            float xo = nom[p][co] * __builtin_amdgcn_rcpf(d + EPSV) + bbv[co];
            xc8[co] = (f16)(xo * cc);
            c8[co] = (f16)cc;
        }
        *(v8h*)(xcout + pa + p * 8) = xc8;
        *(v8h*)(cout + pa + p * 8) = c8;
    }
}

// ---------------------------------------------------------------------------
// Pool-gather NHWC, 2 output pixels per thread.
// ---------------------------------------------------------------------------
__global__ void __launch_bounds__(256) pool_nhwc(
    const f16* __restrict__ xc, const f16* __restrict__ c,
    f16* __restrict__ xo, f16* __restrict__ co_,
    int B, int H, int W) {
    int H2 = H >> 1, W2 = W >> 1, Wh = W2 >> 1;
    int idx = blockIdx.x * 256 + threadIdx.x;
    int total = B * H2 * Wh;
    if (idx >= total) return;
    int wo = (idx % Wh) * 2;
    int ho = (idx / Wh) % H2;
    int b = idx / (Wh * H2);
    unsigned base = (unsigned)(((b * H + 2 * ho) * W + 2 * wo) * 8);
    unsigned rb = (unsigned)(W * 8);
    v8h c0r[4], c1r[4], x0r[4], x1r[4];
#pragma unroll
    for (int i = 0; i < 4; ++i) {
        c0r[i] = *(const v8h*)(c + base + 8 * i);
        c1r[i] = *(const v8h*)(c + base + rb + 8 * i);
        x0r[i] = *(const v8h*)(xc + base + 8 * i);
        x1r[i] = *(const v8h*)(xc + base + rb + 8 * i);
    }
    unsigned oa = (unsigned)(((b * H2 + ho) * W2 + wo) * 8);
#pragma unroll
    for (int p = 0; p < 2; ++p) {
        v8h xr, cr;
#pragma unroll
        for (int e = 0; e < 8; ++e) {
            float b0 = (float)c0r[2 * p][e], b1 = (float)c0r[2 * p + 1][e];
            float b2 = (float)c1r[2 * p][e], b3 = (float)c1r[2 * p + 1][e];
            float cb = b0;
            float xv = (float)x0r[2 * p][e];
            if (b1 > cb) { cb = b1; xv = (float)x0r[2 * p + 1][e]; }
            if (b2 > cb) { cb = b2; xv = (float)x1r[2 * p][e]; }
            if (b3 > cb) { cb = b3; xv = (float)x1r[2 * p + 1][e]; }
            xr[e] = (f16)(xv * 0.25f);
            cr[e] = (f16)(cb * 0.25f);
        }
        *(v8h*)(xo + oa + p * 8) = xr;
        *(v8h*)(co_ + oa + p * 8) = cr;
    }
}

// ---------------------------------------------------------------------------
// Encoder nconv via MFMA with vertical register rotation.
// Groups 0-4 (dh=g-2, dw=sub-2) rotate across h (1 fresh row-load per step);
// groups 5-6 (dw=+2 column) loaded per step. 14 MFMA, 6 loads per tile-row.
// CH must be a multiple of 5.
// ---------------------------------------------------------------------------
__global__ void __launch_bounds__(256) enc5_mfma(
    const f16* __restrict__ xcin, const f16* __restrict__ cin,
    const f16* __restrict__ bfrag, const float* __restrict__ ssum,
    const float* __restrict__ bias,
    f16* __restrict__ xcout, f16* __restrict__ cout,
    int B, int H, int W, int CH) {
    const int lane = threadIdx.x & 63;
    const int wid = threadIdx.x >> 6;
    const int m = lane & 15, sub = lane >> 4;
    const int tilesW = (W + 15) >> 4;
    const int tw = blockIdx.x * 4 + wid;
    if (tw >= tilesW) return;
    const int w0 = tw << 4;
    const int b = blockIdx.z;
    const int h0 = blockIdx.y * CH;

    v8h bf[7];
#pragma unroll
    for (int g = 0; g < 7; ++g)
        bf[g] = *(const v8h*)(bfrag + ((g << 6) + lane) * 8);

    // rotating-group column (dw = sub-2)
    const int cwr = w0 + m + sub - 2;
    const bool okc_r = (cwr >= 0) && (cwr < W);
    const unsigned a_rot = (unsigned)min(max(cwr, 0), W - 1) * 8;
    // edge column (dw = +2)
    const int cwe = w0 + m + 2;
    const bool okc_e = cwe < W;
    const unsigned a_e = (unsigned)min(cwe, W - 1) * 8;

    float4 ssv = {1.f, 1.f, 1.f, 1.f}, bbv = {0.f, 0.f, 0.f, 0.f};
    if (sub < 2) {
        ssv = *(const float4*)(ssum + sub * 4);
        bbv = *(const float4*)(bias + sub * 4);
    }
    float rssv[4];
#pragma unroll
    for (int j = 0; j < 4; ++j) rssv[j] = __builtin_amdgcn_rcpf(((const float*)&ssv)[j]);

    const unsigned W8u = (unsigned)W * 8;
    const unsigned bb8 = (unsigned)(b * H) * W8u;

    // warm-up: slots 0..3 = rows h0-2 .. h0+1
    v8h Rc[5], Rx[5];
#pragma unroll
    for (int t = 0; t < 4; ++t) {
        int r = h0 - 2 + t;
        bool ok = (r >= 0) && (r < H) && okc_r;
        unsigned a = bb8 + (unsigned)min(max(r, 0), H - 1) * W8u + a_rot;
        v8h pc = *(const v8h*)(cin + a);
        v8h px = *(const v8h*)(xcin + a);
        Rc[t] = ok ? pc : v8h_zero();
        Rx[t] = ok ? px : v8h_zero();
    }
    Rc[4] = v8h_zero();
    Rx[4] = v8h_zero();

    unsigned sbase = bb8 + (unsigned)h0 * W8u + (unsigned)(w0 + m) * 8 + sub * 4;
    const bool doStore = (sub < 2) && (w0 + m < W);

    for (int hh = 0; hh < CH; hh += 5) {
#pragma unroll
        for (int p = 0; p < 5; ++p) {
            const int h = h0 + hh + p;
            // fresh rot row h+2 -> slot (p+4)%5
            {
                int r = h + 2;
                bool ok = (r < H) && okc_r;
                unsigned a = bb8 + (unsigned)min(r, H - 1) * W8u + a_rot;
                v8h pc = *(const v8h*)(cin + a);
                v8h px = *(const v8h*)(xcin + a);
                Rc[(p + 4) % 5] = ok ? pc : v8h_zero();
                Rx[(p + 4) % 5] = ok ? px : v8h_zero();
            }
            // g5: per-lane row h+sub-2 @ col +2
            v8h e5c, e5x;
            {
                int r = h + sub - 2;
                bool ok = (r >= 0) && (r < H) && okc_e;
                unsigned a = bb8 + (unsigned)min(max(r, 0), H - 1) * W8u + a_e;
                v8h pc = *(const v8h*)(cin + a);
                v8h px = *(const v8h*)(xcin + a);
                e5c = ok ? pc : v8h_zero();
                e5x = ok ? px : v8h_zero();
            }
            // g6: row h+2 @ col +2 (only sub 0 weights nonzero)
            v8h e6c, e6x;
            {
                int r = h + 2;
                bool ok = (r < H) && okc_e;
                unsigned a = bb8 + (unsigned)min(r, H - 1) * W8u + a_e;
                v8h pc = *(const v8h*)(cin + a);
                v8h px = *(const v8h*)(xcin + a);
                e6c = ok ? pc : v8h_zero();
                e6x = ok ? px : v8h_zero();
            }

            v4f accd = {0.f, 0.f, 0.f, 0.f}, accn = {0.f, 0.f, 0.f, 0.f};
#pragma unroll
            for (int g = 0; g < 5; ++g) {
                accd = __builtin_amdgcn_mfma_f32_16x16x32_f16(bf[g], Rc[(p + g) % 5], accd, 0, 0, 0);
                accn = __builtin_amdgcn_mfma_f32_16x16x32_f16(bf[g], Rx[(p + g) % 5], accn, 0, 0, 0);
            }
            accd = __builtin_amdgcn_mfma_f32_16x16x32_f16(bf[5], e5c, accd, 0, 0, 0);
            accn = __builtin_amdgcn_mfma_f32_16x16x32_f16(bf[5], e5x, accn, 0, 0, 0);
            accd = __builtin_amdgcn_mfma_f32_16x16x32_f16(bf[6], e6c, accd, 0, 0, 0);
            accn = __builtin_amdgcn_mfma_f32_16x16x32_f16(bf[6], e6x, accn, 0, 0, 0);

            if (doStore && h < H) {
                h4 xo8, c8;
#pragma unroll
                for (int j = 0; j < 4; ++j) {
                    float d = accd[j];
                    float cc = d * rssv[j];
                    float x = accn[j] * __builtin_amdgcn_rcpf(d + EPSV) + ((const float*)&bbv)[j];
                    c8[j] = (f16)cc;
                    xo8[j] = (f16)(x * cc);
                }
                *(h4*)(cout + sbase) = c8;
                *(h4*)(xcout + sbase) = xo8;
            }
            sbase += W8u;
        }
    }
}

// ---------------------------------------------------------------------------
// Decoder nconv via MFMA: R = full-res rotating source (GR = its bfrag group
// base), S = half-res source (GS base), 3x3 pad 1, 16ch -> 8ch.
// FUSE7: fused final 1x1 nconv, fp32 1-ch outputs. CH multiple of 3.
// ---------------------------------------------------------------------------
template <int GR, int GS, bool FUSE7>
__global__ void __launch_bounds__(256) dec3_mfma(
    const f16* __restrict__ xcR, const f16* __restrict__ cR,
    const f16* __restrict__ xcS, const f16* __restrict__ cS,
    const f16* __restrict__ bfrag,
    const float* __restrict__ ssum, const float* __restrict__ bias,
    const float* __restrict__ wp7, const float* __restrict__ s7p,
    const float* __restrict__ b7p,
    f16* __restrict__ xcout, f16* __restrict__ ccout,
    float* __restrict__ xoutf, float* __restrict__ coutf,
    int B, int H, int W, int CH) {
    const int lane = threadIdx.x & 63;
    const int wid = threadIdx.x >> 6;
    const int m = lane & 15, sub = lane >> 4;
    const int tilesW = W >> 4;
    const int tw = blockIdx.x * 4 + wid;
    if (tw >= tilesW) return;
    const int w0 = tw << 4;
    const int b = blockIdx.z;
    const int h0 = blockIdx.y * CH;

    v8h bf[6];
#pragma unroll
    for (int g = 0; g < 6; ++g)
        bf[g] = *(const v8h*)(bfrag + ((g << 6) + lane) * 8);

    // column (dw = sub-1; sub==3 slots have zero weights)
    const int cw = w0 + m + sub - 1;
    const bool okc = (cw >= 0) && (cw < W);
    const int cwc = min(max(cw, 0), W - 1);
    const unsigned aR = (unsigned)cwc * 8;
    const unsigned aS = (unsigned)(cwc >> 1) * 8;

    const int Hs = H >> 1, Ws = W >> 1;
    const unsigned WR8 = (unsigned)W * 8;
    const unsigned WS8 = (unsigned)Ws * 8;
    const unsigned bbR = (unsigned)(b * H) * WR8;
    const unsigned bbS = (unsigned)(b * Hs) * WS8;

    float4 ssv = {1.f, 1.f, 1.f, 1.f}, bbv = {0.f, 0.f, 0.f, 0.f};
    float4 w7v = {0.f, 0.f, 0.f, 0.f};
    if (sub < 2) {
        ssv = *(const float4*)(ssum + sub * 4);
        bbv = *(const float4*)(bias + sub * 4);
        if (FUSE7) w7v = *(const float4*)(wp7 + sub * 4);
    }
    float rssv[4];
#pragma unroll
    for (int j = 0; j < 4; ++j) rssv[j] = __builtin_amdgcn_rcpf(((const float*)&ssv)[j]);
    float rs7 = 0.f, b7v = 0.f;
    if (FUSE7) { rs7 = __builtin_amdgcn_rcpf(s7p[0]); b7v = b7p[0]; }

    // warm-up R: slots 0,1 = rows h0-1, h0
    v8h Rc[3], Rx[3];
#pragma unroll
    for (int t = 0; t < 2; ++t) {
        int r = h0 - 1 + t;
        bool ok = (r >= 0) && (r < H) && okc;
        unsigned a = bbR + (unsigned)min(max(r, 0), H - 1) * WR8 + aR;
        v8h pc = *(const v8h*)(cR + a);
        v8h px = *(const v8h*)(xcR + a);
        Rc[t] = ok ? pc : v8h_zero();
        Rx[t] = ok ? px : v8h_zero();
    }
    Rc[2] = v8h_zero();
    Rx[2] = v8h_zero();

    unsigned sbase = bbR + (unsigned)h0 * WR8 + (unsigned)(w0 + m) * 8 + sub * 4;
    const bool doStore = (sub < 2);

    for (int hh = 0; hh < CH; hh += 3) {
#pragma unroll
        for (int p = 0; p < 3; ++p) {
            const int h = h0 + hh + p;
            // fresh R row h+1 -> slot (p+2)%3
            {
                int r = h + 1;
                bool ok = (r < H) && okc;
                unsigned a = bbR + (unsigned)min(r, H - 1) * WR8 + aR;
                v8h pc = *(const v8h*)(cR + a);
                v8h px = *(const v8h*)(xcR + a);
                Rc[(p + 2) % 3] = ok ? pc : v8h_zero();
                Rx[(p + 2) % 3] = ok ? px : v8h_zero();
            }
            // S fragments (3 groups)
            v8h Sc[3], Sx[3];
#pragma unroll
            for (int gs = 0; gs < 3; ++gs) {
                int r = h + gs - 1;
                bool ok = (r >= 0) && (r < H) && okc;
                unsigned a = bbS + (unsigned)(min(max(r, 0), H - 1) >> 1) * WS8 + aS;
                v8h pc = *(const v8h*)(cS + a);
                v8h px = *(const v8h*)(xcS + a);
                Sc[gs] = ok ? pc : v8h_zero();
                Sx[gs] = ok ? px : v8h_zero();
            }

            v4f accd = {0.f, 0.f, 0.f, 0.f}, accn = {0.f, 0.f, 0.f, 0.f};
#pragma unroll
            for (int g = 0; g < 3; ++g) {
                accd = __builtin_amdgcn_mfma_f32_16x16x32_f16(bf[GR + g], Rc[(p + g) % 3], accd, 0, 0, 0);
                accn = __builtin_amdgcn_mfma_f32_16x16x32_f16(bf[GR + g], Rx[(p + g) % 3], accn, 0, 0, 0);
            }
#pragma unroll
            for (int g = 0; g < 3; ++g) {
                accd = __builtin_amdgcn_mfma_f32_16x16x32_f16(bf[GS + g], Sc[g], accd, 0, 0, 0);
                accn = __builtin_amdgcn_mfma_f32_16x16x32_f16(bf[GS + g], Sx[g], accn, 0, 0, 0);
            }

            if (FUSE7) {
                if (h < H) {
                    float td = 0.f, tn = 0.f;
#pragma unroll
                    for (int j = 0; j < 4; ++j) {
                        float d = accd[j];  // 0 for co>=8 (weights zeroed)
                        float cc = d * rssv[j];
                        float o = accn[j] * __builtin_amdgcn_rcpf(d + EPSV) + ((const float*)&bbv)[j];
                        td = fmaf(((const float*)&w7v)[j], cc, td);
                        tn = fmaf(((const float*)&w7v)[j], o * cc, tn);
                    }
                    td += __shfl_xor(td, 16);
                    tn += __shfl_xor(tn, 16);
                    td += __shfl_xor(td, 32);
                    tn += __shfl_xor(tn, 32);
                    unsigned opix = (unsigned)(b * H + h) * (unsigned)W + (unsigned)w0;
                    if (sub == 0) {
                        xoutf[opix + m] = tn * __builtin_amdgcn_rcpf(td + EPSV) + b7v;
                    } else if (sub == 1) {
                        coutf[opix + m] = td * rs7;
                    }
                }
            } else if (doStore && h < H) {
                h4 xo8, c8;
#pragma unroll
                for (int j = 0; j < 4; ++j) {
                    float d = accd[j];
                    float cc = d * rssv[j];
                    float x = accn[j] * __builtin_amdgcn_rcpf(d + EPSV) + ((const float*)&bbv)[j];
                    c8[j] = (f16)cc;
                    xo8[j] = (f16)(x * cc);
                }
                *(h4*)(ccout + sbase) = c8;
                *(h4*)(xcout + sbase) = xo8;
            }
            sbase += WR8;
        }
    }
}

// ---------------------------------------------------------------------------
extern "C" void kernel_launch(void* const* d_in, const int* in_sizes, int n_in,
                              void* d_out, int out_size, void* d_ws, size_t ws_size,
                              hipStream_t stream) {
    const float* x0 = (const float*)d_in[0];
    const float* c0 = (const float*)d_in[1];
    const float* w1 = (const float*)d_in[2];
    const float* b1 = (const float*)d_in[3];
    const float* w2 = (const float*)d_in[4];
    const float* b2 = (const float*)d_in[5];
    const float* w3 = (const float*)d_in[6];
    const float* b3 = (const float*)d_in[7];
    const float* w4 = (const float*)d_in[8];
    const float* b4 = (const float*)d_in[9];
    const float* w5 = (const float*)d_in[10];
    const float* b5 = (const float*)d_in[11];
    const float* w6 = (const float*)d_in[12];
    const float* b6 = (const float*)d_in[13];
    const float* w7 = (const float*)d_in[14];
    const float* b7 = (const float*)d_in[15];

    const int B = 8, H = 352, W = 1216;
    const int H2 = 176, W2 = 608, H4 = 88, W4 = 304, H8 = 44, W8 = 152;
    const size_t F   = (size_t)64 * H * W;
    const size_t H2s = (size_t)64 * H2 * W2;
    const size_t Qs  = (size_t)64 * H4 * W4;
    const size_t Es  = (size_t)64 * H8 * W8;

    const size_t needH = 4 * F * sizeof(f16) + 7168 * sizeof(float);
    if (ws_size < needH) return;

    f16* ws = (f16*)d_ws;
    f16* P0x = ws;            // full-res NHWC (xc, c), persists to final decoder
    f16* P0c = ws + F;
    f16* Ux  = ws + 2 * F;    // full-res ping
    f16* Uc  = ws + 3 * F;
    f16* D1x = ws + 2 * F;    // half-res set aliases region 2
    f16* D1c = D1x + H2s;
    f16* D2x = D1c + H2s;
    f16* D2c = D2x + H2s;
    f16* Q1x = ws + 3 * F;    // quarter + eighth alias region 3
    f16* Q1c = Q1x + Qs;
    f16* Q2x = Q1c + Qs;
    f16* Q2c = Q2x + Qs;
    f16* E1x = Q2c + Qs;
    f16* E1c = E1x + Es;
    f16* E2x = E1c + Es;
    f16* E2c = E2x + Es;
    f16* DF4 = ws + 3 * F + 16777216;  // decoder frags in region-3 slack
    f16* DF5 = DF4 + 3072;
    f16* DF6 = DF5 + 3072;

    char* tail = (char*)d_ws + 4 * F * sizeof(f16);
    float* WT = (float*)tail;
    f16* BF2 = (f16*)(tail + 2048);
    f16* BF3 = (f16*)(tail + 9216);

    const float* s1 = WT + 200;
    const float* s2 = WT + 208;
    const float* s3 = WT + 216;
    const float* s4 = WT + 224;
    const float* s5 = WT + 232;
    const float* s6 = WT + 240;
    const float* s7 = WT + 248;
    const float* wp7 = WT + 256;

    prep_scalars<<<7, 256, 0, stream>>>(w1, w2, w3, w4, w5, w6, w7, WT);
    pack_enc_frag<<<2, 256, 0, stream>>>(w2, w3, BF2, BF3);

    auto nb = [](size_t n) { return (int)((n + 255) / 256); };
    // enc grids: x = ceil(tilesW/4), y = ceil(H/CH) with CH % 5 == 0, z = B.
    const dim3 geF(19, 18, 8);   // tilesW=76, CH=20 (360)
    const dim3 geH(10, 9, 8);    // tilesW=38, CH=20 (180)
    const dim3 geQ(5, 9, 8);     // tilesW=19, CH=10 (90)
    const dim3 geE(3, 9, 8);     // tilesW=10, CH=5  (45)
    // dec grids: CH % 3 == 0.
    const dim3 gdF(19, 15, 8);   // CH=24 (360)
    const dim3 gdH(10, 15, 8);   // CH=12 (180)
    const dim3 gdQ(5, 10, 8);    // CH=9  (90)

    // Encoder
    nconv_l1<<<nb((size_t)B * H * (W / 4)), 256, 0, stream>>>(
        x0, c0, WT, s1, b1, P0x, P0c, B, H, W);
    enc5_mfma<<<geF, 256, 0, stream>>>(P0x, P0c, BF2, s2, b2, Ux, Uc, B, H, W, 20);
    enc5_mfma<<<geF, 256, 0, stream>>>(Ux, Uc, BF3, s3, b3, P0x, P0c, B, H, W, 20);
    pack_dec_frag<<<3, 256, 0, stream>>>(w4, w5, w6, DF4, DF5, DF6);  // Uc dead now
    pool_nhwc<<<nb((size_t)B * H2 * (W2 / 2)), 256, 0, stream>>>(P0x, P0c, D1x, D1c, B, H, W);
    enc5_mfma<<<geH, 256, 0, stream>>>(D1x, D1c, BF2, s2, b2, D2x, D2c, B, H2, W2, 20);
    enc5_mfma<<<geH, 256, 0, stream>>>(D2x, D2c, BF3, s3, b3, D1x, D1c, B, H2, W2, 20);
    pool_nhwc<<<nb((size_t)B * H4 * (W4 / 2)), 256, 0, stream>>>(D1x, D1c, Q1x, Q1c, B, H2, W2);
    enc5_mfma<<<geQ, 256, 0, stream>>>(Q1x, Q1c, BF2, s2, b2, Q2x, Q2c, B, H4, W4, 10);
    pool_nhwc<<<nb((size_t)B * H8 * (W8 / 2)), 256, 0, stream>>>(Q2x, Q2c, E1x, E1c, B, H4, W4);
    enc5_mfma<<<geE, 256, 0, stream>>>(E1x, E1c, BF2, s2, b2, E2x, E2c, B, H8, W8, 5);

    // Decoder: R = full-res rotating source, S = half-res source.
    dec3_mfma<0, 3, false><<<gdQ, 256, 0, stream>>>(
        Q2x, Q2c, E2x, E2c, DF4, s4, b4, WT, WT, WT,
        Q1x, Q1c, (float*)nullptr, (float*)nullptr, B, H4, W4, 9);
    dec3_mfma<0, 3, false><<<gdH, 256, 0, stream>>>(
        D1x, D1c, Q1x, Q1c, DF5, s5, b5, WT, WT, WT,
        D2x, D2c, (float*)nullptr, (float*)nullptr, B, H2, W2, 12);

    float* outx = (float*)d_out;
    float* outc = outx + (size_t)B * H * W;
    dec3_mfma<3, 0, true><<<gdF, 256, 0, stream>>>(
        P0x, P0c, D2x, D2c, DF6, s6, b6, wp7, s7, b7,
        (f16*)nullptr, (f16*)nullptr, outx, outc, B, H, W, 24);
}